// Round 4
// baseline (37505.484 us; speedup 1.0000x reference)
//
#include <hip/hip_runtime.h>
#include <hip/hip_bf16.h>

// SpatialLSTM: B=64, T=2048, D=128, H=256 (4H=1024)
// R4: 4 blocks per batch (256 blocks = 256 CUs). Each block owns 64 h-rows
// (gate cols {q*256+64g+j}) and keeps its U-slice (256x256 f16 = 128 KB)
// LDS-RESIDENT. Per-step h exchange among the 4 sibling blocks via
// agent-scope atomics in d_ws (parity double-buffered). Output f32.
#define BB 64
#define TT 2048
#define DD 128
#define HH 256
#define G4 1024
#define TC 16

typedef _Float16 half2_t __attribute__((ext_vector_type(2)));

#if __has_builtin(__builtin_amdgcn_fdot2)
#define FDOT2(a, b, c) __builtin_amdgcn_fdot2((a), (b), (c), false)
#else
__device__ __forceinline__ float FDOT2(half2_t a, half2_t b, float c) {
    return c + (float)a[0] * (float)b[0] + (float)a[1] * (float)b[1];
}
#endif

__device__ __forceinline__ half2_t u2h(unsigned int u) {
    union { unsigned int u; half2_t h; } x; x.u = u; return x.h;
}
__device__ __forceinline__ unsigned int pkf16(float a, float b) {
    union { _Float16 h[2]; unsigned int u; } x;
    x.h[0] = (_Float16)a; x.h[1] = (_Float16)b; return x.u;
}
__device__ __forceinline__ unsigned short f16b(float a) {
    union { _Float16 h; unsigned short u; } x; x.h = (_Float16)a; return x.u;
}
__device__ __forceinline__ float sigf(float x) {
    return 1.0f / (1.0f + __expf(-x));
}
__device__ __forceinline__ float tanh_fast(float x) {
    return 1.0f - 2.0f / (__expf(2.0f * x) + 1.0f);
}

// ---- zero the sync flags (d_ws is poisoned; must re-init every launch) ----
__global__ void zero_flags(int* flags) {
    if (threadIdx.x < 256) flags[threadIdx.x] = 0;
}

// ---- pack column-slices: src f32 [K][1024] -> dst f16 [g4][c256][kK]
// block (g, kb): 256 threads, thread c packs k in [kb*64, kb*64+64)
__global__ void __launch_bounds__(256)
pack_cols(const float* __restrict__ src, unsigned short* __restrict__ dst, int K)
{
    const int g = blockIdx.x, kb = blockIdx.y, c = threadIdx.x;
    const int gc = ((c >> 6) << 8) + (g << 6) + (c & 63);
    unsigned int* d32 = (unsigned int*)dst;
    const int dbase = ((g << 8) + c) * K + kb * 64;   // half index, even
    for (int kk = 0; kk < 64; kk += 2) {
        const float a = src[(size_t)(kb * 64 + kk) * G4 + gc];
        const float b = src[(size_t)(kb * 64 + kk + 1) * G4 + gc];
        d32[(dbase + kk) >> 1] = pkf16(a, b);
    }
}

// ============================ main kernel ===================================
extern "C" __global__ void __launch_bounds__(512, 2)
lstm_sync(const float* __restrict__ X, const unsigned short* __restrict__ Upack,
          const unsigned short* __restrict__ Wpack, const float* __restrict__ bias,
          const float* __restrict__ h0, const float* __restrict__ c0,
          unsigned int* __restrict__ hglob, int* __restrict__ flags,
          float* __restrict__ out)
{
    __shared__ uint4 Ulds4[HH * 32];                    // 128 KB, swizzled
    __shared__ float xw[TC][256];                       // 16 KB
    __shared__ __align__(16) unsigned short Xs[TC * DD]; // 4 KB
    __shared__ float gvp[2][256];                       // 2 KB
    __shared__ __align__(16) unsigned short hsh[HH];    // 512 B

    const int b = blockIdx.x & 63;
    const int g = blockIdx.x >> 6;
    const int tid = threadIdx.x;
    const int wave = tid >> 6, lane = tid & 63;
    const int c = tid & 255, s = tid >> 8;              // local col, k-half
    const int gc = ((c >> 6) << 8) + (g << 6) + (c & 63);
    const int fbase = b * 4;

    // ---- load U-slice into LDS with XOR swizzle (granule k8 ^ (c&31)) ----
    {
        const uint4* Usrc = (const uint4*)(Upack + (size_t)g * 65536);
        #pragma unroll
        for (int i = 0; i < 16; ++i) {
            const int idx = i * 512 + tid;              // = cc*32 + k8
            const int cc = idx >> 5, k8 = idx & 31;
            Ulds4[cc * 32 + (k8 ^ (cc & 31))] = Usrc[idx];
        }
    }
    if (tid < HH) hsh[tid] = f16b(h0[b * HH + tid]);
    float c_reg = 0.0f, h_last = 0.0f;
    if (wave == 0) {
        c_reg = c0[b * HH + (g << 6) + lane];
        h_last = h0[b * HH + (g << 6) + lane];
    }
    const float bc = bias[gc];
    __syncthreads();

    const unsigned short* Wg = Wpack + (size_t)g * 32768;  // g*256cols*128k

    for (int chunk = 0; chunk < TT / TC; ++chunk) {
        const int t0 = chunk * TC;

        // ---- stage X chunk (f32 -> f16 pairs) ----
        {
            const float4 xv = ((const float4*)(X + ((size_t)b * TT + t0) * DD))[tid];
            ((uint2*)Xs)[tid] = make_uint2(pkf16(xv.x, xv.y), pkf16(xv.z, xv.w));
        }
        __syncthreads();

        // ---- xw[t][c] = X@Wslice + bias; thread (c,s): t in [8s, 8s+8) ----
        {
            float acc[8];
            #pragma unroll
            for (int t = 0; t < 8; ++t) acc[t] = bc;
            const uint4* Wc = (const uint4*)(Wg + (size_t)c * 128);
            #pragma unroll
            for (int k8 = 0; k8 < 16; ++k8) {
                const uint4 w4 = Wc[k8];
                #pragma unroll
                for (int t = 0; t < 8; ++t) {
                    const uint4 xg = *(const uint4*)((const char*)Xs + (s * 8 + t) * 256 + (k8 << 4));
                    acc[t] = FDOT2(u2h(xg.x), u2h(w4.x), acc[t]);
                    acc[t] = FDOT2(u2h(xg.y), u2h(w4.y), acc[t]);
                    acc[t] = FDOT2(u2h(xg.z), u2h(w4.z), acc[t]);
                    acc[t] = FDOT2(u2h(xg.w), u2h(w4.w), acc[t]);
                }
            }
            #pragma unroll
            for (int t = 0; t < 8; ++t) xw[s * 8 + t][c] = acc[t];
        }
        __syncthreads();

        // ---- TC recurrent steps ----
        for (int tt = 0; tt < TC; ++tt) {
            const int tau = t0 + tt;

            // phase A: partial dot over this thread's k-half
            {
                float a0 = (s == 0) ? xw[tt][c] : 0.0f;
                float a1 = 0.0f;
                const int kbase = s << 4;
                #pragma unroll
                for (int i = 0; i < 16; ++i) {
                    const int k8 = kbase + i;
                    const uint4 ug = Ulds4[c * 32 + (k8 ^ (c & 31))];
                    const uint4 hg = *(const uint4*)((const char*)hsh + (k8 << 4));
                    a0 = FDOT2(u2h(ug.x), u2h(hg.x), a0);
                    a1 = FDOT2(u2h(ug.y), u2h(hg.y), a1);
                    a0 = FDOT2(u2h(ug.z), u2h(hg.z), a0);
                    a1 = FDOT2(u2h(ug.w), u2h(hg.w), a1);
                }
                gvp[s][c] = a0 + a1;
            }
            __syncthreads();

            const int par = (tau + 1) & 1;
            if (wave == 0) {
                // phase B: gates -> c,h update; publish own slice
                const int j = lane;
                const float gi = gvp[0][j]       + gvp[1][j];
                const float gf = gvp[0][64 + j]  + gvp[1][64 + j];
                const float gg = gvp[0][128 + j] + gvp[1][128 + j];
                const float go = gvp[0][192 + j] + gvp[1][192 + j];
                const float it = sigf(gi), ft = sigf(gf);
                const float gt = tanh_fast(gg), ot = sigf(go);
                c_reg = fmaf(ft, c_reg, it * gt);
                const float hn = ot * tanh_fast(c_reg);
                h_last = hn;
                out[((size_t)b * TT + tau) * HH + (g << 6) + j] = hn;
                hsh[(g << 6) + j] = f16b(hn);
                const float lo = __shfl(hn, 2 * j);
                const float hi = __shfl(hn, 2 * j + 1);
                if (j < 32) {
                    __hip_atomic_store(&hglob[(((fbase + g) << 1) + par) * 32 + j],
                                       pkf16(lo, hi),
                                       __ATOMIC_RELAXED, __HIP_MEMORY_SCOPE_AGENT);
                }
                if (j == 0) {
                    __hip_atomic_store(&flags[fbase + g], tau + 1,
                                       __ATOMIC_RELEASE, __HIP_MEMORY_SCOPE_AGENT);
                }
            } else if (wave <= 3 && tau < TT - 1) {
                // phase C: fetch one peer's slice for the next step
                const int pg = (g + wave) & 3;
                int spins = 0;
                while (__hip_atomic_load(&flags[fbase + pg], __ATOMIC_ACQUIRE,
                                         __HIP_MEMORY_SCOPE_AGENT) < tau + 1) {
                    __builtin_amdgcn_s_sleep(1);
                    if (++spins > (1 << 20)) break;     // anti-hang: fail fast
                }
                if (lane < 32) {
                    const unsigned int pv = __hip_atomic_load(
                        &hglob[(((fbase + pg) << 1) + par) * 32 + lane],
                        __ATOMIC_RELAXED, __HIP_MEMORY_SCOPE_AGENT);
                    ((unsigned int*)hsh)[(pg << 5) + lane] = pv;
                }
            }
            __syncthreads();
        }
    }

    if (wave == 0) {
        const size_t base = (size_t)BB * TT * HH;
        out[base + (size_t)b * HH + (g << 6) + lane] = h_last;
        out[base + (size_t)BB * HH + (size_t)b * HH + (g << 6) + lane] = c_reg;
    }
}

// ===================== R3 fallback (f16 streaming) ==========================
__global__ void __launch_bounds__(256)
pack_f16(const float* __restrict__ src, unsigned int* __restrict__ dst, int K4)
{
    int idx = blockIdx.x * 256 + threadIdx.x;
    if (idx >= K4 * 512) return;
    const int k4 = idx >> 9, j2 = idx & 511;
    const float* s = src + (size_t)(4 * k4) * G4 + 2 * j2;
    uint4 o;
    o.x = pkf16(s[0 * G4 + 0], s[1 * G4 + 0]);
    o.y = pkf16(s[2 * G4 + 0], s[3 * G4 + 0]);
    o.z = pkf16(s[0 * G4 + 1], s[1 * G4 + 1]);
    o.w = pkf16(s[2 * G4 + 1], s[3 * G4 + 1]);
    reinterpret_cast<uint4*>(dst)[idx] = o;
}

extern "C" __global__ void __launch_bounds__(1024)
lstm_f16(const float* __restrict__ X, const uint4* __restrict__ Upk,
         const uint4* __restrict__ Wpk, const float* __restrict__ bias,
         const float* __restrict__ h0, const float* __restrict__ c0,
         float* __restrict__ out)
{
    __shared__ float xw[TC][G4];
    __shared__ __align__(16) unsigned int Xs[TC][DD / 2];
    __shared__ float gvp2[2][G4];
    __shared__ __align__(8) unsigned short hpk[HH];

    const int b = blockIdx.x;
    const int tid = threadIdx.x;
    const int kg = tid >> 9;
    const int j2 = tid & 511;

    float c_reg = 0.0f, h_last = 0.0f;
    if (tid < HH) {
        const float hv = h0[b * HH + tid];
        hpk[tid] = f16b(hv);
        c_reg = c0[b * HH + tid];
        h_last = hv;
    }
    const float2 bs = reinterpret_cast<const float2*>(bias)[j2];
    __syncthreads();

    for (int chunk = 0; chunk < TT / TC; ++chunk) {
        const int t0 = chunk * TC;
        {
            const float2* src = reinterpret_cast<const float2*>(X + ((size_t)b * TT + t0) * DD);
            const float2 v = src[tid];
            Xs[tid >> 6][tid & 63] = pkf16(v.x, v.y);
        }
        __syncthreads();
        {
            float a0[8], a1[8];
            #pragma unroll
            for (int t = 0; t < 8; ++t) { a0[t] = bs.x; a1[t] = bs.y; }
            #pragma unroll 8
            for (int k4 = 0; k4 < DD / 4; ++k4) {
                const uint4 wp = Wpk[(size_t)k4 * 512 + j2];
                #pragma unroll
                for (int t = 0; t < 8; ++t) {
                    const uint2 xp = *reinterpret_cast<const uint2*>(&Xs[kg * 8 + t][2 * k4]);
                    a0[t] = FDOT2(u2h(xp.x), u2h(wp.x), a0[t]);
                    a0[t] = FDOT2(u2h(xp.y), u2h(wp.y), a0[t]);
                    a1[t] = FDOT2(u2h(xp.x), u2h(wp.z), a1[t]);
                    a1[t] = FDOT2(u2h(xp.y), u2h(wp.w), a1[t]);
                }
            }
            #pragma unroll
            for (int t = 0; t < 8; ++t)
                *reinterpret_cast<float2*>(&xw[kg * 8 + t][2 * j2]) = make_float2(a0[t], a1[t]);
        }
        __syncthreads();

        for (int t = 0; t < TC; ++t) {
            float a0, a1;
            if (kg == 0) {
                const float2 x2 = *reinterpret_cast<const float2*>(&xw[t][2 * j2]);
                a0 = x2.x; a1 = x2.y;
            } else { a0 = 0.0f; a1 = 0.0f; }
            #pragma unroll
            for (int k4 = 0; k4 < 32; ++k4) {
                const int gk4 = kg * 32 + k4;
                const uint4 up = Upk[(size_t)gk4 * 512 + j2];
                const uint2 hp = *reinterpret_cast<const uint2*>(&hpk[4 * gk4]);
                a0 = FDOT2(u2h(hp.x), u2h(up.x), a0);
                a0 = FDOT2(u2h(hp.y), u2h(up.y), a0);
                a1 = FDOT2(u2h(hp.x), u2h(up.z), a1);
                a1 = FDOT2(u2h(hp.y), u2h(up.w), a1);
            }
            *reinterpret_cast<float2*>(&gvp2[kg][2 * j2]) = make_float2(a0, a1);
            __syncthreads();
            if (tid < HH) {
                const float gi = gvp2[0][tid] + gvp2[1][tid];
                const float gf = gvp2[0][tid + HH] + gvp2[1][tid + HH];
                const float gg = gvp2[0][tid + 2 * HH] + gvp2[1][tid + 2 * HH];
                const float go = gvp2[0][tid + 3 * HH] + gvp2[1][tid + 3 * HH];
                const float it = sigf(gi), ft = sigf(gf);
                const float gt = tanh_fast(gg), ot = sigf(go);
                c_reg = fmaf(ft, c_reg, it * gt);
                const float hn = ot * tanh_fast(c_reg);
                h_last = hn;
                out[((size_t)b * TT + (t0 + t)) * HH + tid] = hn;
                hpk[tid] = f16b(hn);
            }
            __syncthreads();
        }
    }
    if (tid < HH) {
        const size_t base = (size_t)BB * TT * HH;
        out[base + (size_t)b * HH + tid] = h_last;
        out[base + (size_t)BB * HH + (size_t)b * HH + tid] = c_reg;
    }
}

// ===================== R2 fallback (f32, no workspace) ======================
extern "C" __global__ void __launch_bounds__(512)
lstm_persist(const float* __restrict__ X, const float* __restrict__ W,
             const float* __restrict__ U, const float* __restrict__ bias,
             const float* __restrict__ h0, const float* __restrict__ c0,
             float* __restrict__ out)
{
    __shared__ float xw[TC][G4];
    __shared__ float Xs[TC][DD];
    __shared__ float hsh[HH];
    __shared__ float gv[G4];

    const int b = blockIdx.x;
    const int tid = threadIdx.x;
    const float2* __restrict__ U2 = reinterpret_cast<const float2*>(U);
    const float2* __restrict__ W2 = reinterpret_cast<const float2*>(W);

    float c_reg = 0.0f;
    if (tid < HH) { hsh[tid] = h0[b * HH + tid]; c_reg = c0[b * HH + tid]; }
    const float2 bs = reinterpret_cast<const float2*>(bias)[tid];
    __syncthreads();

    for (int chunk = 0; chunk < TT / TC; ++chunk) {
        const int t0 = chunk * TC;
        {
            const float4* src = reinterpret_cast<const float4*>(X + ((size_t)b * TT + t0) * DD);
            float4* dst = reinterpret_cast<float4*>(&Xs[0][0]);
            for (int i = tid; i < TC * DD / 4; i += 512) dst[i] = src[i];
        }
        __syncthreads();
        float acc0[TC], acc1[TC];
        #pragma unroll
        for (int t = 0; t < TC; ++t) { acc0[t] = bs.x; acc1[t] = bs.y; }
        for (int kk = 0; kk < DD; kk += 4) {
            const float2 w0 = W2[(size_t)(kk + 0) * (G4 / 2) + tid];
            const float2 w1 = W2[(size_t)(kk + 1) * (G4 / 2) + tid];
            const float2 w2 = W2[(size_t)(kk + 2) * (G4 / 2) + tid];
            const float2 w3 = W2[(size_t)(kk + 3) * (G4 / 2) + tid];
            #pragma unroll
            for (int t = 0; t < TC; ++t) {
                const float4 xv = *reinterpret_cast<const float4*>(&Xs[t][kk]);
                acc0[t] = fmaf(xv.x, w0.x, acc0[t]); acc1[t] = fmaf(xv.x, w0.y, acc1[t]);
                acc0[t] = fmaf(xv.y, w1.x, acc0[t]); acc1[t] = fmaf(xv.y, w1.y, acc1[t]);
                acc0[t] = fmaf(xv.z, w2.x, acc0[t]); acc1[t] = fmaf(xv.z, w2.y, acc1[t]);
                acc0[t] = fmaf(xv.w, w3.x, acc0[t]); acc1[t] = fmaf(xv.w, w3.y, acc1[t]);
            }
        }
        #pragma unroll
        for (int t = 0; t < TC; ++t)
            *reinterpret_cast<float2*>(&xw[t][2 * tid]) = make_float2(acc0[t], acc1[t]);
        __syncthreads();

        for (int t = 0; t < TC; ++t) {
            const float2 x2 = *reinterpret_cast<const float2*>(&xw[t][2 * tid]);
            float a0 = x2.x, a1 = x2.y;
            #pragma unroll 4
            for (int k = 0; k < HH; k += 4) {
                const float4 hk = *reinterpret_cast<const float4*>(&hsh[k]);
                const float2 u0 = U2[(size_t)(k + 0) * (G4 / 2) + tid];
                const float2 u1 = U2[(size_t)(k + 1) * (G4 / 2) + tid];
                const float2 u2 = U2[(size_t)(k + 2) * (G4 / 2) + tid];
                const float2 u3 = U2[(size_t)(k + 3) * (G4 / 2) + tid];
                a0 = fmaf(hk.x, u0.x, a0); a1 = fmaf(hk.x, u0.y, a1);
                a0 = fmaf(hk.y, u1.x, a0); a1 = fmaf(hk.y, u1.y, a1);
                a0 = fmaf(hk.z, u2.x, a0); a1 = fmaf(hk.z, u2.y, a1);
                a0 = fmaf(hk.w, u3.x, a0); a1 = fmaf(hk.w, u3.y, a1);
            }
            *reinterpret_cast<float2*>(&gv[2 * tid]) = make_float2(a0, a1);
            __syncthreads();
            if (tid < HH) {
                const float it = sigf(gv[tid]);
                const float ft = sigf(gv[tid + HH]);
                const float gt = tanh_fast(gv[tid + 2 * HH]);
                const float ot = sigf(gv[tid + 3 * HH]);
                c_reg = fmaf(ft, c_reg, it * gt);
                const float hn = ot * tanh_fast(c_reg);
                hsh[tid] = hn;
                out[((size_t)b * TT + (t0 + t)) * HH + tid] = hn;
            }
            __syncthreads();
        }
    }
    if (tid < HH) {
        const size_t base = (size_t)BB * TT * HH;
        out[base + (size_t)b * HH + tid] = hsh[tid];
        out[base + (size_t)BB * HH + (size_t)b * HH + tid] = c_reg;
    }
}

extern "C" void kernel_launch(void* const* d_in, const int* in_sizes, int n_in,
                              void* d_out, int out_size, void* d_ws, size_t ws_size,
                              hipStream_t stream) {
    const float* X    = (const float*)d_in[0];
    const float* W    = (const float*)d_in[1];
    const float* U    = (const float*)d_in[2];
    const float* bias = (const float*)d_in[3];
    const float* h0   = (const float*)d_in[4];
    const float* c0   = (const float*)d_in[5];
    float* out = (float*)d_out;
    (void)in_sizes; (void)n_in; (void)out_size;

    const size_t upk = 512 * 1024;     // Upack f16 [4][256][256]
    const size_t wpk = 256 * 1024;     // Wpack f16 [4][256][128]
    const size_t hgl = 64 * 1024;      // hglob [64][4][2][32] uints
    const size_t flg = 1024;           // flags [256]

    if (ws_size >= upk + wpk + hgl + flg) {
        unsigned short* Upack = (unsigned short*)d_ws;
        unsigned short* Wpack = (unsigned short*)((char*)d_ws + upk);
        unsigned int*   hglob = (unsigned int*)((char*)d_ws + upk + wpk);
        int*            flags = (int*)((char*)d_ws + upk + wpk + hgl);
        zero_flags<<<dim3(1), dim3(256), 0, stream>>>(flags);
        pack_cols<<<dim3(4, 4), dim3(256), 0, stream>>>(U, Upack, 256);
        pack_cols<<<dim3(4, 2), dim3(256), 0, stream>>>(W, Wpack, 128);
        lstm_sync<<<dim3(256), dim3(512), 0, stream>>>(
            X, Upack, Wpack, bias, h0, c0, hglob, flags, out);
    } else if (ws_size >= 768 * 1024) {
        unsigned int* Upk = (unsigned int*)d_ws;
        unsigned int* Wpk = (unsigned int*)((char*)d_ws + 512 * 1024);
        pack_f16<<<dim3((HH / 4) * 512 / 256), dim3(256), 0, stream>>>(U, Upk, HH / 4);
        pack_f16<<<dim3((DD / 4) * 512 / 256), dim3(256), 0, stream>>>(W, Wpk, DD / 4);
        lstm_f16<<<dim3(BB), dim3(1024), 0, stream>>>(
            X, (const uint4*)Upk, (const uint4*)Wpk, bias, h0, c0, out);
    } else {
        lstm_persist<<<dim3(BB), dim3(512), 0, stream>>>(X, W, U, bias, h0, c0, out);
    }
}

// Round 5
// 4497.488 us; speedup vs baseline: 8.3392x; 8.3392x over previous
//
#include <hip/hip_runtime.h>
#include <hip/hip_bf16.h>

// SpatialLSTM: B=64, T=2048, D=128, H=256 (4H=1024)
// R5: R4 structure (4 blocks/batch, U-slice LDS-resident, per-step h exchange)
// with a fixed sync protocol: RELAXED agent atomics only (no acquire/release
// -> no buffer_inv cache-invalidation storm), hand-rolled ordering via
// s_waitcnt vmcnt(0), padded flags, publish-first, no sleep in poll.
#define BB 64
#define TT 2048
#define DD 128
#define HH 256
#define G4 1024
#define TC 16

typedef _Float16 half2_t __attribute__((ext_vector_type(2)));

#if __has_builtin(__builtin_amdgcn_fdot2)
#define FDOT2(a, b, c) __builtin_amdgcn_fdot2((a), (b), (c), false)
#else
__device__ __forceinline__ float FDOT2(half2_t a, half2_t b, float c) {
    return c + (float)a[0] * (float)b[0] + (float)a[1] * (float)b[1];
}
#endif

__device__ __forceinline__ half2_t u2h(unsigned int u) {
    union { unsigned int u; half2_t h; } x; x.u = u; return x.h;
}
__device__ __forceinline__ unsigned int pkf16(float a, float b) {
    union { _Float16 h[2]; unsigned int u; } x;
    x.h[0] = (_Float16)a; x.h[1] = (_Float16)b; return x.u;
}
__device__ __forceinline__ unsigned short f16b(float a) {
    union { _Float16 h; unsigned short u; } x; x.h = (_Float16)a; return x.u;
}
__device__ __forceinline__ float sigf(float x) {
    return 1.0f / (1.0f + __expf(-x));
}
__device__ __forceinline__ float tanh_fast(float x) {
    return 1.0f - 2.0f / (__expf(2.0f * x) + 1.0f);
}

// ---- zero the padded sync flags (d_ws poisoned; re-init every launch) ----
__global__ void zero_flags(int* flags) {
    flags[blockIdx.x * 256 + threadIdx.x] = 0;
}

// ---- pack column-slices: src f32 [K][1024] -> dst f16 [g4][c256][kK]
__global__ void __launch_bounds__(256)
pack_cols(const float* __restrict__ src, unsigned short* __restrict__ dst, int K)
{
    const int g = blockIdx.x, kb = blockIdx.y, c = threadIdx.x;
    const int gc = ((c >> 6) << 8) + (g << 6) + (c & 63);
    unsigned int* d32 = (unsigned int*)dst;
    const int dbase = ((g << 8) + c) * K + kb * 64;   // half index, even
    for (int kk = 0; kk < 64; kk += 2) {
        const float a = src[(size_t)(kb * 64 + kk) * G4 + gc];
        const float b = src[(size_t)(kb * 64 + kk + 1) * G4 + gc];
        d32[(dbase + kk) >> 1] = pkf16(a, b);
    }
}

// ============================ main kernel ===================================
extern "C" __global__ void __launch_bounds__(512, 2)
lstm_sync(const float* __restrict__ X, const unsigned short* __restrict__ Upack,
          const unsigned short* __restrict__ Wpack, const float* __restrict__ bias,
          const float* __restrict__ h0, const float* __restrict__ c0,
          unsigned int* __restrict__ hglob, int* __restrict__ flags,
          float* __restrict__ out)
{
    __shared__ uint4 Ulds4[HH * 32];                    // 128 KB, swizzled
    __shared__ float xw[TC][256];                       // 16 KB
    __shared__ __align__(16) unsigned short Xs[TC * DD]; // 4 KB
    __shared__ float gvp[2][256];                       // 2 KB
    __shared__ __align__(16) unsigned short hsh[HH];    // 512 B

    const int b = blockIdx.x & 63;        // siblings {b+64g} share XCD (latency)
    const int g = blockIdx.x >> 6;
    const int tid = threadIdx.x;
    const int wave = tid >> 6, lane = tid & 63;
    const int c = tid & 255, s = tid >> 8;              // local col, k-half
    const int gc = ((c >> 6) << 8) + (g << 6) + (c & 63);
    const int fbase = b * 4;

    // ---- load U-slice into LDS with XOR swizzle (granule k8 ^ (c&31)) ----
    {
        const uint4* Usrc = (const uint4*)(Upack + (size_t)g * 65536);
        #pragma unroll
        for (int i = 0; i < 16; ++i) {
            const int idx = i * 512 + tid;              // = cc*32 + k8
            const int cc = idx >> 5, k8 = idx & 31;
            Ulds4[cc * 32 + (k8 ^ (cc & 31))] = Usrc[idx];
        }
    }
    if (tid < HH) hsh[tid] = f16b(h0[b * HH + tid]);
    float c_reg = 0.0f, h_last = 0.0f;
    if (wave == 0) {
        c_reg = c0[b * HH + (g << 6) + lane];
        h_last = h0[b * HH + (g << 6) + lane];
    }
    const float bc = bias[gc];
    __syncthreads();

    const unsigned short* Wg = Wpack + (size_t)g * 32768;  // g*256cols*128k

    for (int chunk = 0; chunk < TT / TC; ++chunk) {
        const int t0 = chunk * TC;

        // ---- stage X chunk (f32 -> f16 pairs) ----
        {
            const float4 xv = ((const float4*)(X + ((size_t)b * TT + t0) * DD))[tid];
            ((uint2*)Xs)[tid] = make_uint2(pkf16(xv.x, xv.y), pkf16(xv.z, xv.w));
        }
        __syncthreads();

        // ---- xw[t][c] = X@Wslice + bias; thread (c,s): t in [8s, 8s+8) ----
        {
            float acc[8];
            #pragma unroll
            for (int t = 0; t < 8; ++t) acc[t] = bc;
            const uint4* Wc = (const uint4*)(Wg + (size_t)c * 128);
            #pragma unroll
            for (int k8 = 0; k8 < 16; ++k8) {
                const uint4 w4 = Wc[k8];
                #pragma unroll
                for (int t = 0; t < 8; ++t) {
                    const uint4 xg = *(const uint4*)((const char*)Xs + (s * 8 + t) * 256 + (k8 << 4));
                    acc[t] = FDOT2(u2h(xg.x), u2h(w4.x), acc[t]);
                    acc[t] = FDOT2(u2h(xg.y), u2h(w4.y), acc[t]);
                    acc[t] = FDOT2(u2h(xg.z), u2h(w4.z), acc[t]);
                    acc[t] = FDOT2(u2h(xg.w), u2h(w4.w), acc[t]);
                }
            }
            #pragma unroll
            for (int t = 0; t < 8; ++t) xw[s * 8 + t][c] = acc[t];
        }
        __syncthreads();

        // ---- TC recurrent steps ----
        for (int tt = 0; tt < TC; ++tt) {
            const int tau = t0 + tt;

            // phase A: partial dot over this thread's k-half
            {
                float a0 = (s == 0) ? xw[tt][c] : 0.0f;
                float a1 = 0.0f;
                const int kbase = s << 4;
                #pragma unroll
                for (int i = 0; i < 16; ++i) {
                    const int k8 = kbase + i;
                    const uint4 ug = Ulds4[c * 32 + (k8 ^ (c & 31))];
                    const uint4 hg = *(const uint4*)((const char*)hsh + (k8 << 4));
                    a0 = FDOT2(u2h(ug.x), u2h(hg.x), a0);
                    a1 = FDOT2(u2h(ug.y), u2h(hg.y), a1);
                    a0 = FDOT2(u2h(ug.z), u2h(hg.z), a0);
                    a1 = FDOT2(u2h(ug.w), u2h(hg.w), a1);
                }
                gvp[s][c] = a0 + a1;
            }
            __syncthreads();

            const int par = (tau + 1) & 1;
            if (wave == 0) {
                // phase B: gates -> c,h update; publish FIRST, then out/hsh
                const int j = lane;
                const float gi = gvp[0][j]       + gvp[1][j];
                const float gf = gvp[0][64 + j]  + gvp[1][64 + j];
                const float gg = gvp[0][128 + j] + gvp[1][128 + j];
                const float go = gvp[0][192 + j] + gvp[1][192 + j];
                const float it = sigf(gi), ft = sigf(gf);
                const float gt = tanh_fast(gg), ot = sigf(go);
                c_reg = fmaf(ft, c_reg, it * gt);
                const float hn = ot * tanh_fast(c_reg);
                h_last = hn;
                const float lo = __shfl(hn, 2 * j);
                const float hi = __shfl(hn, 2 * j + 1);
                if (j < 32) {
                    __hip_atomic_store(&hglob[(((fbase + g) << 1) + par) * 32 + j],
                                       pkf16(lo, hi),
                                       __ATOMIC_RELAXED, __HIP_MEMORY_SCOPE_AGENT);
                }
                // drain data stores to the coherence point, then raise flag
                asm volatile("s_waitcnt vmcnt(0)" ::: "memory");
                if (j == 0) {
                    __hip_atomic_store(&flags[(fbase + g) * 8], tau + 1,
                                       __ATOMIC_RELAXED, __HIP_MEMORY_SCOPE_AGENT);
                }
                out[((size_t)b * TT + tau) * HH + (g << 6) + j] = hn;
                hsh[(g << 6) + j] = f16b(hn);
            } else if (wave <= 3 && tau < TT - 1) {
                // phase C: fetch one peer's slice for the next step
                const int pg = (g + wave) & 3;
                int spins = 0;
                while (__hip_atomic_load(&flags[(fbase + pg) * 8], __ATOMIC_RELAXED,
                                         __HIP_MEMORY_SCOPE_AGENT) < tau + 1) {
                    if (++spins > (1 << 20)) break;     // anti-hang: fail fast
                }
                if (lane < 32) {
                    const unsigned int pv = __hip_atomic_load(
                        &hglob[(((fbase + pg) << 1) + par) * 32 + lane],
                        __ATOMIC_RELAXED, __HIP_MEMORY_SCOPE_AGENT);
                    ((unsigned int*)hsh)[(pg << 5) + lane] = pv;
                }
            }
            __syncthreads();
        }
    }

    if (wave == 0) {
        const size_t base = (size_t)BB * TT * HH;
        out[base + (size_t)b * HH + (g << 6) + lane] = h_last;
        out[base + (size_t)BB * HH + (size_t)b * HH + (g << 6) + lane] = c_reg;
    }
}

// ===================== R3 fallback (f16 streaming) ==========================
__global__ void __launch_bounds__(256)
pack_f16(const float* __restrict__ src, unsigned int* __restrict__ dst, int K4)
{
    int idx = blockIdx.x * 256 + threadIdx.x;
    if (idx >= K4 * 512) return;
    const int k4 = idx >> 9, j2 = idx & 511;
    const float* s = src + (size_t)(4 * k4) * G4 + 2 * j2;
    uint4 o;
    o.x = pkf16(s[0 * G4 + 0], s[1 * G4 + 0]);
    o.y = pkf16(s[2 * G4 + 0], s[3 * G4 + 0]);
    o.z = pkf16(s[0 * G4 + 1], s[1 * G4 + 1]);
    o.w = pkf16(s[2 * G4 + 1], s[3 * G4 + 1]);
    reinterpret_cast<uint4*>(dst)[idx] = o;
}

extern "C" __global__ void __launch_bounds__(1024)
lstm_f16(const float* __restrict__ X, const uint4* __restrict__ Upk,
         const uint4* __restrict__ Wpk, const float* __restrict__ bias,
         const float* __restrict__ h0, const float* __restrict__ c0,
         float* __restrict__ out)
{
    __shared__ float xw[TC][G4];
    __shared__ __align__(16) unsigned int Xs[TC][DD / 2];
    __shared__ float gvp2[2][G4];
    __shared__ __align__(8) unsigned short hpk[HH];

    const int b = blockIdx.x;
    const int tid = threadIdx.x;
    const int kg = tid >> 9;
    const int j2 = tid & 511;

    float c_reg = 0.0f, h_last = 0.0f;
    if (tid < HH) {
        const float hv = h0[b * HH + tid];
        hpk[tid] = f16b(hv);
        c_reg = c0[b * HH + tid];
        h_last = hv;
    }
    const float2 bs = reinterpret_cast<const float2*>(bias)[j2];
    __syncthreads();

    for (int chunk = 0; chunk < TT / TC; ++chunk) {
        const int t0 = chunk * TC;
        {
            const float2* src = reinterpret_cast<const float2*>(X + ((size_t)b * TT + t0) * DD);
            const float2 v = src[tid];
            Xs[tid >> 6][tid & 63] = pkf16(v.x, v.y);
        }
        __syncthreads();
        {
            float a0[8], a1[8];
            #pragma unroll
            for (int t = 0; t < 8; ++t) { a0[t] = bs.x; a1[t] = bs.y; }
            #pragma unroll 8
            for (int k4 = 0; k4 < DD / 4; ++k4) {
                const uint4 wp = Wpk[(size_t)k4 * 512 + j2];
                #pragma unroll
                for (int t = 0; t < 8; ++t) {
                    const uint2 xp = *reinterpret_cast<const uint2*>(&Xs[kg * 8 + t][2 * k4]);
                    a0[t] = FDOT2(u2h(xp.x), u2h(wp.x), a0[t]);
                    a0[t] = FDOT2(u2h(xp.y), u2h(wp.y), a0[t]);
                    a1[t] = FDOT2(u2h(xp.x), u2h(wp.z), a1[t]);
                    a1[t] = FDOT2(u2h(xp.y), u2h(wp.w), a1[t]);
                }
            }
            #pragma unroll
            for (int t = 0; t < 8; ++t)
                *reinterpret_cast<float2*>(&xw[kg * 8 + t][2 * j2]) = make_float2(a0[t], a1[t]);
        }
        __syncthreads();

        for (int t = 0; t < TC; ++t) {
            float a0, a1;
            if (kg == 0) {
                const float2 x2 = *reinterpret_cast<const float2*>(&xw[t][2 * j2]);
                a0 = x2.x; a1 = x2.y;
            } else { a0 = 0.0f; a1 = 0.0f; }
            #pragma unroll
            for (int k4 = 0; k4 < 32; ++k4) {
                const int gk4 = kg * 32 + k4;
                const uint4 up = Upk[(size_t)gk4 * 512 + j2];
                const uint2 hp = *reinterpret_cast<const uint2*>(&hpk[4 * gk4]);
                a0 = FDOT2(u2h(hp.x), u2h(up.x), a0);
                a0 = FDOT2(u2h(hp.y), u2h(up.y), a0);
                a1 = FDOT2(u2h(hp.x), u2h(up.z), a1);
                a1 = FDOT2(u2h(hp.y), u2h(up.w), a1);
            }
            *reinterpret_cast<float2*>(&gvp2[kg][2 * j2]) = make_float2(a0, a1);
            __syncthreads();
            if (tid < HH) {
                const float gi = gvp2[0][tid] + gvp2[1][tid];
                const float gf = gvp2[0][tid + HH] + gvp2[1][tid + HH];
                const float gg = gvp2[0][tid + 2 * HH] + gvp2[1][tid + 2 * HH];
                const float go = gvp2[0][tid + 3 * HH] + gvp2[1][tid + 3 * HH];
                const float it = sigf(gi), ft = sigf(gf);
                const float gt = tanh_fast(gg), ot = sigf(go);
                c_reg = fmaf(ft, c_reg, it * gt);
                const float hn = ot * tanh_fast(c_reg);
                h_last = hn;
                out[((size_t)b * TT + (t0 + t)) * HH + tid] = hn;
                hpk[tid] = f16b(hn);
            }
            __syncthreads();
        }
    }
    if (tid < HH) {
        const size_t base = (size_t)BB * TT * HH;
        out[base + (size_t)b * HH + tid] = h_last;
        out[base + (size_t)BB * HH + (size_t)b * HH + tid] = c_reg;
    }
}

// ===================== R2 fallback (f32, no workspace) ======================
extern "C" __global__ void __launch_bounds__(512)
lstm_persist(const float* __restrict__ X, const float* __restrict__ W,
             const float* __restrict__ U, const float* __restrict__ bias,
             const float* __restrict__ h0, const float* __restrict__ c0,
             float* __restrict__ out)
{
    __shared__ float xw[TC][G4];
    __shared__ float Xs[TC][DD];
    __shared__ float hsh[HH];
    __shared__ float gv[G4];

    const int b = blockIdx.x;
    const int tid = threadIdx.x;
    const float2* __restrict__ U2 = reinterpret_cast<const float2*>(U);
    const float2* __restrict__ W2 = reinterpret_cast<const float2*>(W);

    float c_reg = 0.0f;
    if (tid < HH) { hsh[tid] = h0[b * HH + tid]; c_reg = c0[b * HH + tid]; }
    const float2 bs = reinterpret_cast<const float2*>(bias)[tid];
    __syncthreads();

    for (int chunk = 0; chunk < TT / TC; ++chunk) {
        const int t0 = chunk * TC;
        {
            const float4* src = reinterpret_cast<const float4*>(X + ((size_t)b * TT + t0) * DD);
            float4* dst = reinterpret_cast<float4*>(&Xs[0][0]);
            for (int i = tid; i < TC * DD / 4; i += 512) dst[i] = src[i];
        }
        __syncthreads();
        float acc0[TC], acc1[TC];
        #pragma unroll
        for (int t = 0; t < TC; ++t) { acc0[t] = bs.x; acc1[t] = bs.y; }
        for (int kk = 0; kk < DD; kk += 4) {
            const float2 w0 = W2[(size_t)(kk + 0) * (G4 / 2) + tid];
            const float2 w1 = W2[(size_t)(kk + 1) * (G4 / 2) + tid];
            const float2 w2 = W2[(size_t)(kk + 2) * (G4 / 2) + tid];
            const float2 w3 = W2[(size_t)(kk + 3) * (G4 / 2) + tid];
            #pragma unroll
            for (int t = 0; t < TC; ++t) {
                const float4 xv = *reinterpret_cast<const float4*>(&Xs[t][kk]);
                acc0[t] = fmaf(xv.x, w0.x, acc0[t]); acc1[t] = fmaf(xv.x, w0.y, acc1[t]);
                acc0[t] = fmaf(xv.y, w1.x, acc0[t]); acc1[t] = fmaf(xv.y, w1.y, acc1[t]);
                acc0[t] = fmaf(xv.z, w2.x, acc0[t]); acc1[t] = fmaf(xv.z, w2.y, acc1[t]);
                acc0[t] = fmaf(xv.w, w3.x, acc0[t]); acc1[t] = fmaf(xv.w, w3.y, acc1[t]);
            }
        }
        #pragma unroll
        for (int t = 0; t < TC; ++t)
            *reinterpret_cast<float2*>(&xw[t][2 * tid]) = make_float2(acc0[t], acc1[t]);
        __syncthreads();

        for (int t = 0; t < TC; ++t) {
            const float2 x2 = *reinterpret_cast<const float2*>(&xw[t][2 * tid]);
            float a0 = x2.x, a1 = x2.y;
            #pragma unroll 4
            for (int k = 0; k < HH; k += 4) {
                const float4 hk = *reinterpret_cast<const float4*>(&hsh[k]);
                const float2 u0 = U2[(size_t)(k + 0) * (G4 / 2) + tid];
                const float2 u1 = U2[(size_t)(k + 1) * (G4 / 2) + tid];
                const float2 u2 = U2[(size_t)(k + 2) * (G4 / 2) + tid];
                const float2 u3 = U2[(size_t)(k + 3) * (G4 / 2) + tid];
                a0 = fmaf(hk.x, u0.x, a0); a1 = fmaf(hk.x, u0.y, a1);
                a0 = fmaf(hk.y, u1.x, a0); a1 = fmaf(hk.y, u1.y, a1);
                a0 = fmaf(hk.z, u2.x, a0); a1 = fmaf(hk.z, u2.y, a1);
                a0 = fmaf(hk.w, u3.x, a0); a1 = fmaf(hk.w, u3.y, a1);
            }
            *reinterpret_cast<float2*>(&gv[2 * tid]) = make_float2(a0, a1);
            __syncthreads();
            if (tid < HH) {
                const float it = sigf(gv[tid]);
                const float ft = sigf(gv[tid + HH]);
                const float gt = tanh_fast(gv[tid + 2 * HH]);
                const float ot = sigf(gv[tid + 3 * HH]);
                c_reg = fmaf(ft, c_reg, it * gt);
                const float hn = ot * tanh_fast(c_reg);
                hsh[tid] = hn;
                out[((size_t)b * TT + (t0 + t)) * HH + tid] = hn;
            }
            __syncthreads();
        }
    }
    if (tid < HH) {
        const size_t base = (size_t)BB * TT * HH;
        out[base + (size_t)b * HH + tid] = hsh[tid];
        out[base + (size_t)BB * HH + (size_t)b * HH + tid] = c_reg;
    }
}

extern "C" void kernel_launch(void* const* d_in, const int* in_sizes, int n_in,
                              void* d_out, int out_size, void* d_ws, size_t ws_size,
                              hipStream_t stream) {
    const float* X    = (const float*)d_in[0];
    const float* W    = (const float*)d_in[1];
    const float* U    = (const float*)d_in[2];
    const float* bias = (const float*)d_in[3];
    const float* h0   = (const float*)d_in[4];
    const float* c0   = (const float*)d_in[5];
    float* out = (float*)d_out;
    (void)in_sizes; (void)n_in; (void)out_size;

    const size_t upk = 512 * 1024;     // Upack f16 [4][256][256]
    const size_t wpk = 256 * 1024;     // Wpack f16 [4][256][128]
    const size_t hgl = 64 * 1024;      // hglob [64][4][2][32] uints
    const size_t flg = 8 * 1024;       // flags [256] padded x8 (32 B apart)

    if (ws_size >= upk + wpk + hgl + flg) {
        unsigned short* Upack = (unsigned short*)d_ws;
        unsigned short* Wpack = (unsigned short*)((char*)d_ws + upk);
        unsigned int*   hglob = (unsigned int*)((char*)d_ws + upk + wpk);
        int*            flags = (int*)((char*)d_ws + upk + wpk + hgl);
        zero_flags<<<dim3(8), dim3(256), 0, stream>>>(flags);
        pack_cols<<<dim3(4, 4), dim3(256), 0, stream>>>(U, Upack, 256);
        pack_cols<<<dim3(4, 2), dim3(256), 0, stream>>>(W, Wpack, 128);
        lstm_sync<<<dim3(256), dim3(512), 0, stream>>>(
            X, Upack, Wpack, bias, h0, c0, hglob, flags, out);
    } else if (ws_size >= 768 * 1024) {
        unsigned int* Upk = (unsigned int*)d_ws;
        unsigned int* Wpk = (unsigned int*)((char*)d_ws + 512 * 1024);
        pack_f16<<<dim3((HH / 4) * 512 / 256), dim3(256), 0, stream>>>(U, Upk, HH / 4);
        pack_f16<<<dim3((DD / 4) * 512 / 256), dim3(256), 0, stream>>>(W, Wpk, DD / 4);
        lstm_f16<<<dim3(BB), dim3(1024), 0, stream>>>(
            X, (const uint4*)Upk, (const uint4*)Wpk, bias, h0, c0, out);
    } else {
        lstm_persist<<<dim3(BB), dim3(512), 0, stream>>>(X, W, U, bias, h0, c0, out);
    }
}

// Round 6
// 3960.317 us; speedup vs baseline: 9.4703x; 1.1356x over previous
//
#include <hip/hip_runtime.h>
#include <hip/hip_bf16.h>

// SpatialLSTM: B=64, T=2048, D=128, H=256 (4H=1024)
// R6: 8 slices x 32 batch-pairs = 256 blocks. Each block: 2 batches, 128 gate
// cols, U-slice (64KB) + W-slice (32KB) LDS-resident. Per-step h exchange via
// fused 8B packets {f32 h, u32 counter} -- no flag, no vmcnt drain, poll IS
// the data read. Parity double-buffered (provably WAR-safe). Output f32.
#define BB 64
#define TT 2048
#define DD 128
#define HH 256
#define G4 1024
#define TC 16

typedef _Float16 half2_t __attribute__((ext_vector_type(2)));

#if __has_builtin(__builtin_amdgcn_fdot2)
#define FDOT2(a, b, c) __builtin_amdgcn_fdot2((a), (b), (c), false)
#else
__device__ __forceinline__ float FDOT2(half2_t a, half2_t b, float c) {
    return c + (float)a[0] * (float)b[0] + (float)a[1] * (float)b[1];
}
#endif

__device__ __forceinline__ half2_t u2h(unsigned int u) {
    union { unsigned int u; half2_t h; } x; x.u = u; return x.h;
}
__device__ __forceinline__ unsigned int pkf16(float a, float b) {
    union { _Float16 h[2]; unsigned int u; } x;
    x.h[0] = (_Float16)a; x.h[1] = (_Float16)b; return x.u;
}
__device__ __forceinline__ unsigned short f16b(float a) {
    union { _Float16 h; unsigned short u; } x; x.h = (_Float16)a; return x.u;
}
__device__ __forceinline__ float sigf(float x) {
    return 1.0f / (1.0f + __expf(-x));
}
__device__ __forceinline__ float tanh_fast(float x) {
    return 1.0f - 2.0f / (__expf(2.0f * x) + 1.0f);
}

// ---- zero the packet buffer (counters must start < 1 every launch) ----
__global__ void zero_hglob(unsigned long long* hglob) {
    hglob[blockIdx.x * 256 + threadIdx.x] = 0ull;
}

// ---- pack slice-columns: src f32 [K][1024] -> dst f16 [8 slices][128 c][K]
// local col c of slice g <-> global gate col (c>>5)*256 + g*32 + (c&31)
__global__ void __launch_bounds__(128)
pack_slices(const float* __restrict__ src, unsigned short* __restrict__ dst, int K)
{
    const int g = blockIdx.x, kb = blockIdx.y, c = threadIdx.x;
    const int gc = ((c >> 5) << 8) + (g << 5) + (c & 31);
    unsigned int* d32 = (unsigned int*)dst;
    const int dbase = ((g << 7) + c) * K + kb * 64;     // half index, even
    for (int kk = 0; kk < 64; kk += 2) {
        const float a = src[(size_t)(kb * 64 + kk) * G4 + gc];
        const float b = src[(size_t)(kb * 64 + kk + 1) * G4 + gc];
        d32[(dbase + kk) >> 1] = pkf16(a, b);
    }
}

// ============================ main kernel ===================================
// grid 256: pair = blk&31 (2 batches), g = blk>>5 (slice of 128 gate cols)
extern "C" __global__ void __launch_bounds__(512, 2)
lstm_pair(const float* __restrict__ X, const unsigned short* __restrict__ Upack,
          const unsigned short* __restrict__ Wpack, const float* __restrict__ bias,
          const float* __restrict__ h0, const float* __restrict__ c0,
          unsigned long long* __restrict__ hglob, float* __restrict__ out)
{
    __shared__ __align__(16) uint4 Ulds4[128 * 32];      // 64 KB, swizzled
    __shared__ __align__(16) uint4 Wlds4[128 * 16];      // 32 KB, swizzled
    __shared__ float xw[2][TC][128];                     // 16 KB
    __shared__ __align__(16) unsigned short Xs[2 * TC * DD]; // 8 KB (f16)
    __shared__ float gvp[2][4][128];                     // 4 KB partials
    __shared__ __align__(16) unsigned short hsh[2 * HH]; // 1 KB (f16 h, 2 batches)

    const int pair = blockIdx.x & 31;
    const int g = blockIdx.x >> 5;
    const int b0 = pair * 2;
    const int tid = threadIdx.x;
    const int wave = tid >> 6, lane = tid & 63;
    const int c = tid & 127, s = tid >> 7;               // local col, k-quarter

    // ---- stage U-slice (swizzle granule gr^(c&31)) and W-slice (gr^(c&15)) --
    {
        const uint4* Usrc = (const uint4*)(Upack + (size_t)g * 32768);
        #pragma unroll
        for (int i = 0; i < 8; ++i) {
            const int idx = i * 512 + tid;               // cc*32 + gr
            const int cc = idx >> 5, gr = idx & 31;
            Ulds4[cc * 32 + (gr ^ (cc & 31))] = Usrc[idx];
        }
        const uint4* Wsrc = (const uint4*)(Wpack + (size_t)g * 16384);
        #pragma unroll
        for (int i = 0; i < 4; ++i) {
            const int idx = i * 512 + tid;               // cc*16 + gr
            const int cc = idx >> 4, gr = idx & 15;
            Wlds4[cc * 16 + (gr ^ (cc & 15))] = Wsrc[idx];
        }
    }
    // hsh init: thread -> (p = tid>>8, k = tid&255)
    hsh[tid] = f16b(h0[(size_t)(b0 + (tid >> 8)) * HH + (tid & 255)]);
    float c_reg = 0.0f, h_last = 0.0f;
    if (wave == 0) {
        const int p = lane >> 5, j = lane & 31;
        c_reg = c0[(size_t)(b0 + p) * HH + (g << 5) + j];
        h_last = h0[(size_t)(b0 + p) * HH + (g << 5) + j];
    }
    const float bc = bias[((c >> 5) << 8) + (g << 5) + (c & 31)];
    __syncthreads();

    for (int chunk = 0; chunk < TT / TC; ++chunk) {
        const int t0 = chunk * TC;

        // ---- stage X chunk for 2 batches (f32 -> f16 pairs) ----
        #pragma unroll
        for (int r = 0; r < 2; ++r) {
            const float4 xv = ((const float4*)(X + ((size_t)(b0 + r) * TT + t0) * DD))[tid];
            ((uint2*)Xs)[r * 512 + tid] = make_uint2(pkf16(xv.x, xv.y), pkf16(xv.z, xv.w));
        }
        __syncthreads();

        // ---- xw[p][t][c] = X@Wslice + bias; thread (c,s): p=s>>1, t-half=s&1
        {
            const int p = s >> 1, th = s & 1;
            float acc[8];
            #pragma unroll
            for (int t = 0; t < 8; ++t) acc[t] = bc;
            #pragma unroll
            for (int k8 = 0; k8 < 16; ++k8) {
                const uint4 w4 = Wlds4[c * 16 + (k8 ^ (c & 15))];
                #pragma unroll
                for (int t = 0; t < 8; ++t) {
                    const uint4 xg = *(const uint4*)((const char*)Xs +
                                     ((p * 16 + th * 8 + t) << 8) + (k8 << 4));
                    acc[t] = FDOT2(u2h(xg.x), u2h(w4.x), acc[t]);
                    acc[t] = FDOT2(u2h(xg.y), u2h(w4.y), acc[t]);
                    acc[t] = FDOT2(u2h(xg.z), u2h(w4.z), acc[t]);
                    acc[t] = FDOT2(u2h(xg.w), u2h(w4.w), acc[t]);
                }
            }
            #pragma unroll
            for (int t = 0; t < 8; ++t) xw[p][th * 8 + t][c] = acc[t];
        }
        __syncthreads();

        // ---- TC recurrent steps ----
        for (int tt2 = 0; tt2 < TC; ++tt2) {
            const int tau = t0 + tt2;

            // phase A: both batches' partial dot over this thread's k-quarter
            {
                float a0 = (s == 0) ? xw[0][tt2][c] : 0.0f;
                float a1 = (s == 0) ? xw[1][tt2][c] : 0.0f;
                #pragma unroll
                for (int ii = 0; ii < 8; ++ii) {
                    const uint4 ug = Ulds4[c * 32 + ((s * 8 + ii) ^ (c & 31))];
                    const uint4 hg0 = *(const uint4*)((const char*)hsh + (s << 7) + (ii << 4));
                    const uint4 hg1 = *(const uint4*)((const char*)hsh + 512 + (s << 7) + (ii << 4));
                    a0 = FDOT2(u2h(ug.x), u2h(hg0.x), a0);
                    a1 = FDOT2(u2h(ug.x), u2h(hg1.x), a1);
                    a0 = FDOT2(u2h(ug.y), u2h(hg0.y), a0);
                    a1 = FDOT2(u2h(ug.y), u2h(hg1.y), a1);
                    a0 = FDOT2(u2h(ug.z), u2h(hg0.z), a0);
                    a1 = FDOT2(u2h(ug.z), u2h(hg1.z), a1);
                    a0 = FDOT2(u2h(ug.w), u2h(hg0.w), a0);
                    a1 = FDOT2(u2h(ug.w), u2h(hg1.w), a1);
                }
                gvp[0][s][c] = a0;
                gvp[1][s][c] = a1;
            }
            __syncthreads();

            const int par = (tau + 1) & 1;
            if (wave == 0) {
                // gates -> c,h; publish fused packet {h, tau+1}; no drain
                const int p = lane >> 5, j = lane & 31;
                const float* gv = &gvp[p][0][0];
                float gi = 0.f, gf = 0.f, gg = 0.f, go = 0.f;
                #pragma unroll
                for (int qs = 0; qs < 4; ++qs) {
                    gi += gv[qs * 128 + j];
                    gf += gv[qs * 128 + 32 + j];
                    gg += gv[qs * 128 + 64 + j];
                    go += gv[qs * 128 + 96 + j];
                }
                const float it = sigf(gi), ft = sigf(gf);
                const float gt = tanh_fast(gg), ot = sigf(go);
                c_reg = fmaf(ft, c_reg, it * gt);
                const float hn = ot * tanh_fast(c_reg);
                h_last = hn;
                const unsigned long long pkt =
                    ((unsigned long long)(unsigned)(tau + 1) << 32) |
                    (unsigned long long)__float_as_uint(hn);
                __hip_atomic_store(&hglob[((((pair << 3) + g) << 1) + par) * 64 + lane],
                                   pkt, __ATOMIC_RELAXED, __HIP_MEMORY_SCOPE_AGENT);
                out[((size_t)(b0 + p) * TT + tau) * HH + (g << 5) + j] = hn;
                hsh[(p << 8) + (g << 5) + j] = f16b(hn);
            } else if (tau < TT - 1) {
                // poll one peer's fused packets; the poll IS the data read
                const int pg = (g + wave) & 7;
                const int p = lane >> 5, j = lane & 31;
                const unsigned long long* q =
                    &hglob[((((pair << 3) + pg) << 1) + par) * 64 + lane];
                unsigned long long v;
                int spins = 0;
                do {
                    v = __hip_atomic_load(q, __ATOMIC_RELAXED, __HIP_MEMORY_SCOPE_AGENT);
                    if (++spins > (1 << 20)) break;      // anti-hang: fail fast
                } while ((unsigned)(v >> 32) != (unsigned)(tau + 1));
                hsh[(p << 8) + (pg << 5) + j] = f16b(__uint_as_float((unsigned)v));
            }
            __syncthreads();
        }
    }

    if (wave == 0) {
        const int p = lane >> 5, j = lane & 31;
        const size_t base = (size_t)BB * TT * HH;
        out[base + (size_t)(b0 + p) * HH + (g << 5) + j] = h_last;
        out[base + (size_t)BB * HH + (size_t)(b0 + p) * HH + (g << 5) + j] = c_reg;
    }
}

// ================= R5 fallback (4 blocks/batch, flag+data) ==================
__global__ void zero_flags(int* flags) {
    flags[blockIdx.x * 256 + threadIdx.x] = 0;
}

__global__ void __launch_bounds__(256)
pack_cols(const float* __restrict__ src, unsigned short* __restrict__ dst, int K)
{
    const int g = blockIdx.x, kb = blockIdx.y, c = threadIdx.x;
    const int gc = ((c >> 6) << 8) + (g << 6) + (c & 63);
    unsigned int* d32 = (unsigned int*)dst;
    const int dbase = ((g << 8) + c) * K + kb * 64;
    for (int kk = 0; kk < 64; kk += 2) {
        const float a = src[(size_t)(kb * 64 + kk) * G4 + gc];
        const float b = src[(size_t)(kb * 64 + kk + 1) * G4 + gc];
        d32[(dbase + kk) >> 1] = pkf16(a, b);
    }
}

extern "C" __global__ void __launch_bounds__(512, 2)
lstm_sync(const float* __restrict__ X, const unsigned short* __restrict__ Upack,
          const unsigned short* __restrict__ Wpack, const float* __restrict__ bias,
          const float* __restrict__ h0, const float* __restrict__ c0,
          unsigned int* __restrict__ hglob, int* __restrict__ flags,
          float* __restrict__ out)
{
    __shared__ uint4 Ulds4[HH * 32];
    __shared__ float xw[TC][256];
    __shared__ __align__(16) unsigned short Xs[TC * DD];
    __shared__ float gvp[2][256];
    __shared__ __align__(16) unsigned short hsh[HH];

    const int b = blockIdx.x & 63;
    const int g = blockIdx.x >> 6;
    const int tid = threadIdx.x;
    const int wave = tid >> 6, lane = tid & 63;
    const int c = tid & 255, s = tid >> 8;
    const int gc = ((c >> 6) << 8) + (g << 6) + (c & 63);
    const int fbase = b * 4;

    {
        const uint4* Usrc = (const uint4*)(Upack + (size_t)g * 65536);
        #pragma unroll
        for (int i = 0; i < 16; ++i) {
            const int idx = i * 512 + tid;
            const int cc = idx >> 5, k8 = idx & 31;
            Ulds4[cc * 32 + (k8 ^ (cc & 31))] = Usrc[idx];
        }
    }
    if (tid < HH) hsh[tid] = f16b(h0[b * HH + tid]);
    float c_reg = 0.0f, h_last = 0.0f;
    if (wave == 0) {
        c_reg = c0[b * HH + (g << 6) + lane];
        h_last = h0[b * HH + (g << 6) + lane];
    }
    const float bc = bias[gc];
    __syncthreads();

    const unsigned short* Wg = Wpack + (size_t)g * 32768;

    for (int chunk = 0; chunk < TT / TC; ++chunk) {
        const int t0 = chunk * TC;
        {
            const float4 xv = ((const float4*)(X + ((size_t)b * TT + t0) * DD))[tid];
            ((uint2*)Xs)[tid] = make_uint2(pkf16(xv.x, xv.y), pkf16(xv.z, xv.w));
        }
        __syncthreads();
        {
            float acc[8];
            #pragma unroll
            for (int t = 0; t < 8; ++t) acc[t] = bc;
            const uint4* Wc = (const uint4*)(Wg + (size_t)c * 128);
            #pragma unroll
            for (int k8 = 0; k8 < 16; ++k8) {
                const uint4 w4 = Wc[k8];
                #pragma unroll
                for (int t = 0; t < 8; ++t) {
                    const uint4 xg = *(const uint4*)((const char*)Xs + (s * 8 + t) * 256 + (k8 << 4));
                    acc[t] = FDOT2(u2h(xg.x), u2h(w4.x), acc[t]);
                    acc[t] = FDOT2(u2h(xg.y), u2h(w4.y), acc[t]);
                    acc[t] = FDOT2(u2h(xg.z), u2h(w4.z), acc[t]);
                    acc[t] = FDOT2(u2h(xg.w), u2h(w4.w), acc[t]);
                }
            }
            #pragma unroll
            for (int t = 0; t < 8; ++t) xw[s * 8 + t][c] = acc[t];
        }
        __syncthreads();

        for (int tt = 0; tt < TC; ++tt) {
            const int tau = t0 + tt;
            {
                float a0 = (s == 0) ? xw[tt][c] : 0.0f;
                float a1 = 0.0f;
                const int kbase = s << 4;
                #pragma unroll
                for (int i = 0; i < 16; ++i) {
                    const int k8 = kbase + i;
                    const uint4 ug = Ulds4[c * 32 + (k8 ^ (c & 31))];
                    const uint4 hg = *(const uint4*)((const char*)hsh + (k8 << 4));
                    a0 = FDOT2(u2h(ug.x), u2h(hg.x), a0);
                    a1 = FDOT2(u2h(ug.y), u2h(hg.y), a1);
                    a0 = FDOT2(u2h(ug.z), u2h(hg.z), a0);
                    a1 = FDOT2(u2h(ug.w), u2h(hg.w), a1);
                }
                gvp[s][c] = a0 + a1;
            }
            __syncthreads();

            const int par = (tau + 1) & 1;
            if (wave == 0) {
                const int j = lane;
                const float gi = gvp[0][j]       + gvp[1][j];
                const float gf = gvp[0][64 + j]  + gvp[1][64 + j];
                const float gg = gvp[0][128 + j] + gvp[1][128 + j];
                const float go = gvp[0][192 + j] + gvp[1][192 + j];
                const float it = sigf(gi), ft = sigf(gf);
                const float gt = tanh_fast(gg), ot = sigf(go);
                c_reg = fmaf(ft, c_reg, it * gt);
                const float hn = ot * tanh_fast(c_reg);
                h_last = hn;
                const float lo = __shfl(hn, 2 * j);
                const float hi = __shfl(hn, 2 * j + 1);
                if (j < 32) {
                    __hip_atomic_store(&hglob[(((fbase + g) << 1) + par) * 32 + j],
                                       pkf16(lo, hi),
                                       __ATOMIC_RELAXED, __HIP_MEMORY_SCOPE_AGENT);
                }
                asm volatile("s_waitcnt vmcnt(0)" ::: "memory");
                if (j == 0) {
                    __hip_atomic_store(&flags[(fbase + g) * 8], tau + 1,
                                       __ATOMIC_RELAXED, __HIP_MEMORY_SCOPE_AGENT);
                }
                out[((size_t)b * TT + tau) * HH + (g << 6) + j] = hn;
                hsh[(g << 6) + j] = f16b(hn);
            } else if (wave <= 3 && tau < TT - 1) {
                const int pg = (g + wave) & 3;
                int spins = 0;
                while (__hip_atomic_load(&flags[(fbase + pg) * 8], __ATOMIC_RELAXED,
                                         __HIP_MEMORY_SCOPE_AGENT) < tau + 1) {
                    if (++spins > (1 << 20)) break;
                }
                if (lane < 32) {
                    const unsigned int pv = __hip_atomic_load(
                        &hglob[(((fbase + pg) << 1) + par) * 32 + lane],
                        __ATOMIC_RELAXED, __HIP_MEMORY_SCOPE_AGENT);
                    ((unsigned int*)hsh)[(pg << 5) + lane] = pv;
                }
            }
            __syncthreads();
        }
    }

    if (wave == 0) {
        const size_t base = (size_t)BB * TT * HH;
        out[base + (size_t)b * HH + (g << 6) + lane] = h_last;
        out[base + (size_t)BB * HH + (size_t)b * HH + (g << 6) + lane] = c_reg;
    }
}

// ===================== R2 fallback (f32, no workspace) ======================
extern "C" __global__ void __launch_bounds__(512)
lstm_persist(const float* __restrict__ X, const float* __restrict__ W,
             const float* __restrict__ U, const float* __restrict__ bias,
             const float* __restrict__ h0, const float* __restrict__ c0,
             float* __restrict__ out)
{
    __shared__ float xw[TC][G4];
    __shared__ float Xs[TC][DD];
    __shared__ float hsh[HH];
    __shared__ float gv[G4];

    const int b = blockIdx.x;
    const int tid = threadIdx.x;
    const float2* __restrict__ U2 = reinterpret_cast<const float2*>(U);
    const float2* __restrict__ W2 = reinterpret_cast<const float2*>(W);

    float c_reg = 0.0f;
    if (tid < HH) { hsh[tid] = h0[b * HH + tid]; c_reg = c0[b * HH + tid]; }
    const float2 bs = reinterpret_cast<const float2*>(bias)[tid];
    __syncthreads();

    for (int chunk = 0; chunk < TT / TC; ++chunk) {
        const int t0 = chunk * TC;
        {
            const float4* src = reinterpret_cast<const float4*>(X + ((size_t)b * TT + t0) * DD);
            float4* dst = reinterpret_cast<float4*>(&Xs[0][0]);
            for (int i = tid; i < TC * DD / 4; i += 512) dst[i] = src[i];
        }
        __syncthreads();
        float acc0[TC], acc1[TC];
        #pragma unroll
        for (int t = 0; t < TC; ++t) { acc0[t] = bs.x; acc1[t] = bs.y; }
        for (int kk = 0; kk < DD; kk += 4) {
            const float2 w0 = W2[(size_t)(kk + 0) * (G4 / 2) + tid];
            const float2 w1 = W2[(size_t)(kk + 1) * (G4 / 2) + tid];
            const float2 w2 = W2[(size_t)(kk + 2) * (G4 / 2) + tid];
            const float2 w3 = W2[(size_t)(kk + 3) * (G4 / 2) + tid];
            #pragma unroll
            for (int t = 0; t < TC; ++t) {
                const float4 xv = *reinterpret_cast<const float4*>(&Xs[t][kk]);
                acc0[t] = fmaf(xv.x, w0.x, acc0[t]); acc1[t] = fmaf(xv.x, w0.y, acc1[t]);
                acc0[t] = fmaf(xv.y, w1.x, acc0[t]); acc1[t] = fmaf(xv.y, w1.y, acc1[t]);
                acc0[t] = fmaf(xv.z, w2.x, acc0[t]); acc1[t] = fmaf(xv.z, w2.y, acc1[t]);
                acc0[t] = fmaf(xv.w, w3.x, acc0[t]); acc1[t] = fmaf(xv.w, w3.y, acc1[t]);
            }
        }
        #pragma unroll
        for (int t = 0; t < TC; ++t)
            *reinterpret_cast<float2*>(&xw[t][2 * tid]) = make_float2(acc0[t], acc1[t]);
        __syncthreads();

        for (int t = 0; t < TC; ++t) {
            const float2 x2 = *reinterpret_cast<const float2*>(&xw[t][2 * tid]);
            float a0 = x2.x, a1 = x2.y;
            #pragma unroll 4
            for (int k = 0; k < HH; k += 4) {
                const float4 hk = *reinterpret_cast<const float4*>(&hsh[k]);
                const float2 u0 = U2[(size_t)(k + 0) * (G4 / 2) + tid];
                const float2 u1 = U2[(size_t)(k + 1) * (G4 / 2) + tid];
                const float2 u2 = U2[(size_t)(k + 2) * (G4 / 2) + tid];
                const float2 u3 = U2[(size_t)(k + 3) * (G4 / 2) + tid];
                a0 = fmaf(hk.x, u0.x, a0); a1 = fmaf(hk.x, u0.y, a1);
                a0 = fmaf(hk.y, u1.x, a0); a1 = fmaf(hk.y, u1.y, a1);
                a0 = fmaf(hk.z, u2.x, a0); a1 = fmaf(hk.z, u2.y, a1);
                a0 = fmaf(hk.w, u3.x, a0); a1 = fmaf(hk.w, u3.y, a1);
            }
            *reinterpret_cast<float2*>(&gv[2 * tid]) = make_float2(a0, a1);
            __syncthreads();
            if (tid < HH) {
                const float it = sigf(gv[tid]);
                const float ft = sigf(gv[tid + HH]);
                const float gt = tanh_fast(gv[tid + 2 * HH]);
                const float ot = sigf(gv[tid + 3 * HH]);
                c_reg = fmaf(ft, c_reg, it * gt);
                const float hn = ot * tanh_fast(c_reg);
                hsh[tid] = hn;
                out[((size_t)b * TT + (t0 + t)) * HH + tid] = hn;
            }
            __syncthreads();
        }
    }
    if (tid < HH) {
        const size_t base = (size_t)BB * TT * HH;
        out[base + (size_t)b * HH + tid] = hsh[tid];
        out[base + (size_t)BB * HH + (size_t)b * HH + tid] = c_reg;
    }
}

extern "C" void kernel_launch(void* const* d_in, const int* in_sizes, int n_in,
                              void* d_out, int out_size, void* d_ws, size_t ws_size,
                              hipStream_t stream) {
    const float* X    = (const float*)d_in[0];
    const float* W    = (const float*)d_in[1];
    const float* U    = (const float*)d_in[2];
    const float* bias = (const float*)d_in[3];
    const float* h0   = (const float*)d_in[4];
    const float* c0   = (const float*)d_in[5];
    float* out = (float*)d_out;
    (void)in_sizes; (void)n_in; (void)out_size;

    // --- R6 path: 1 MB workspace ---
    const size_t upk6 = 512 * 1024;    // Upack f16 [8][128][256]
    const size_t wpk6 = 256 * 1024;    // Wpack f16 [8][128][128]
    const size_t hgl6 = 256 * 1024;    // hglob u64 [32][8][2][64]
    if (ws_size >= upk6 + wpk6 + hgl6) {
        unsigned short* Upack = (unsigned short*)d_ws;
        unsigned short* Wpack = (unsigned short*)((char*)d_ws + upk6);
        unsigned long long* hglob = (unsigned long long*)((char*)d_ws + upk6 + wpk6);
        zero_hglob<<<dim3(128), dim3(256), 0, stream>>>(hglob);
        pack_slices<<<dim3(8, 4), dim3(128), 0, stream>>>(U, Upack, 256);
        pack_slices<<<dim3(8, 2), dim3(128), 0, stream>>>(W, Wpack, 128);
        lstm_pair<<<dim3(256), dim3(512), 0, stream>>>(
            X, Upack, Wpack, bias, h0, c0, hglob, out);
        return;
    }

    // --- R5 fallback: 840.5 KB ---
    const size_t upk = 512 * 1024;
    const size_t wpk = 256 * 1024;
    const size_t hgl = 64 * 1024;
    const size_t flg = 8 * 1024;
    if (ws_size >= upk + wpk + hgl + flg) {
        unsigned short* Upack = (unsigned short*)d_ws;
        unsigned short* Wpack = (unsigned short*)((char*)d_ws + upk);
        unsigned int*   hglob = (unsigned int*)((char*)d_ws + upk + wpk);
        int*            flags = (int*)((char*)d_ws + upk + wpk + hgl);
        zero_flags<<<dim3(8), dim3(256), 0, stream>>>(flags);
        pack_cols<<<dim3(4, 4), dim3(256), 0, stream>>>(U, Upack, 256);
        pack_cols<<<dim3(4, 2), dim3(256), 0, stream>>>(W, Wpack, 128);
        lstm_sync<<<dim3(256), dim3(512), 0, stream>>>(
            X, Upack, Wpack, bias, h0, c0, hglob, flags, out);
        return;
    }

    // --- R2 fallback: no workspace ---
    lstm_persist<<<dim3(BB), dim3(512), 0, stream>>>(X, W, U, bias, h0, c0, out);
}

// Round 7
// 3552.810 us; speedup vs baseline: 10.5566x; 1.1147x over previous
//
#include <hip/hip_runtime.h>
#include <hip/hip_bf16.h>

// SpatialLSTM: B=64, T=2048, D=128, H=256 (4H=1024)
// R7: R6 decomposition (8 slices x 32 batch-pairs = 256 blocks; U/W slices
// LDS-resident; fused {f32 h, u32 counter} packets, parity double-buffered)
// + two latency cuts:
//   1) lgkm-only barriers (no vmcnt(0) store-ack drain per step)
//   2) batch-pipelined slots: A0 | gates0+pubP0 || pollP1 | A1 | gates1+pubP1
//      || pollP0  -- each poll fires one phase-A after its publish, hiding
//      the LLC flight under compute.
#define BB 64
#define TT 2048
#define DD 128
#define HH 256
#define G4 1024
#define TC 16

typedef _Float16 half2_t __attribute__((ext_vector_type(2)));

#if __has_builtin(__builtin_amdgcn_fdot2)
#define FDOT2(a, b, c) __builtin_amdgcn_fdot2((a), (b), (c), false)
#else
__device__ __forceinline__ float FDOT2(half2_t a, half2_t b, float c) {
    return c + (float)a[0] * (float)b[0] + (float)a[1] * (float)b[1];
}
#endif

__device__ __forceinline__ half2_t u2h(unsigned int u) {
    union { unsigned int u; half2_t h; } x; x.u = u; return x.h;
}
__device__ __forceinline__ unsigned int pkf16(float a, float b) {
    union { _Float16 h[2]; unsigned int u; } x;
    x.h[0] = (_Float16)a; x.h[1] = (_Float16)b; return x.u;
}
__device__ __forceinline__ unsigned short f16b(float a) {
    union { _Float16 h; unsigned short u; } x; x.h = (_Float16)a; return x.u;
}
__device__ __forceinline__ float sigf(float x) {
    return 1.0f / (1.0f + __expf(-x));
}
__device__ __forceinline__ float tanh_fast(float x) {
    return 1.0f - 2.0f / (__expf(2.0f * x) + 1.0f);
}
// LDS-ordering-only barrier: skip the vmcnt(0) store-ack drain __syncthreads
// would impose (nothing in-block reads our global stores; peers poll).
__device__ __forceinline__ void bar_lgkm() {
    asm volatile("s_waitcnt lgkmcnt(0)\n\ts_barrier" ::: "memory");
}

// ---- zero the packet buffer (counters must start < 1 every launch) ----
__global__ void zero_hglob(unsigned long long* hglob) {
    hglob[blockIdx.x * 256 + threadIdx.x] = 0ull;
}

// ---- pack slice-columns: src f32 [K][1024] -> dst f16 [8 slices][128 c][K]
// local col c of slice g <-> global gate col (c>>5)*256 + g*32 + (c&31)
__global__ void __launch_bounds__(128)
pack_slices(const float* __restrict__ src, unsigned short* __restrict__ dst, int K)
{
    const int g = blockIdx.x, kb = blockIdx.y, c = threadIdx.x;
    const int gc = ((c >> 5) << 8) + (g << 5) + (c & 31);
    unsigned int* d32 = (unsigned int*)dst;
    const int dbase = ((g << 7) + c) * K + kb * 64;     // half index, even
    for (int kk = 0; kk < 64; kk += 2) {
        const float a = src[(size_t)(kb * 64 + kk) * G4 + gc];
        const float b = src[(size_t)(kb * 64 + kk + 1) * G4 + gc];
        d32[(dbase + kk) >> 1] = pkf16(a, b);
    }
}

// ============================ main kernel ===================================
// grid 256: pair = blk&31 (2 batches), g = blk>>5 (slice of 32 gate cols x4)
extern "C" __global__ void __launch_bounds__(512, 2)
lstm_pipe(const float* __restrict__ X, const unsigned short* __restrict__ Upack,
          const unsigned short* __restrict__ Wpack, const float* __restrict__ bias,
          const float* __restrict__ h0, const float* __restrict__ c0,
          unsigned long long* __restrict__ hglob, float* __restrict__ out)
{
    __shared__ __align__(16) uint4 Ulds4[128 * 32];      // 64 KB, swizzled
    __shared__ __align__(16) uint4 Wlds4[128 * 16];      // 32 KB, swizzled
    __shared__ float xw[2][TC][128];                     // 16 KB
    __shared__ __align__(16) unsigned short Xs[2 * TC * DD]; // 8 KB (f16)
    __shared__ float gvp[4][128];                        // 2 KB partials
    __shared__ __align__(16) unsigned short hsh[2 * HH]; // 1 KB (f16 h per batch)

    const int pair = blockIdx.x & 31;
    const int g = blockIdx.x >> 5;
    const int b0 = pair * 2;
    const int tid = threadIdx.x;
    const int wave = tid >> 6, lane = tid & 63;
    const int c = tid & 127, s = tid >> 7;               // local col, k-quarter

    // ---- stage U-slice (swizzle granule gr^(c&31)) and W-slice (gr^(c&15)) --
    {
        const uint4* Usrc = (const uint4*)(Upack + (size_t)g * 32768);
        #pragma unroll
        for (int i = 0; i < 8; ++i) {
            const int idx = i * 512 + tid;               // cc*32 + gr
            const int cc = idx >> 5, gr = idx & 31;
            Ulds4[cc * 32 + (gr ^ (cc & 31))] = Usrc[idx];
        }
        const uint4* Wsrc = (const uint4*)(Wpack + (size_t)g * 16384);
        #pragma unroll
        for (int i = 0; i < 4; ++i) {
            const int idx = i * 512 + tid;               // cc*16 + gr
            const int cc = idx >> 4, gr = idx & 15;
            Wlds4[cc * 16 + (gr ^ (cc & 15))] = Wsrc[idx];
        }
    }
    hsh[tid] = f16b(h0[(size_t)(b0 + (tid >> 8)) * HH + (tid & 255)]);
    float c_reg0 = 0.0f, c_reg1 = 0.0f, h_last0 = 0.0f, h_last1 = 0.0f;
    if (wave == 0 && lane < 32) {
        c_reg0 = c0[(size_t)b0 * HH + (g << 5) + lane];
        c_reg1 = c0[(size_t)(b0 + 1) * HH + (g << 5) + lane];
        h_last0 = h0[(size_t)b0 * HH + (g << 5) + lane];
        h_last1 = h0[(size_t)(b0 + 1) * HH + (g << 5) + lane];
    }
    const float bc = bias[((c >> 5) << 8) + (g << 5) + (c & 31)];
    __syncthreads();

    const size_t obase0 = (size_t)b0 * TT * HH + (g << 5);
    const size_t obase1 = (size_t)(b0 + 1) * TT * HH + (g << 5);
    const int slotbase = ((pair << 3) + g) << 1;          // *64 packets

    for (int chunk = 0; chunk < TT / TC; ++chunk) {
        const int t0 = chunk * TC;

        // ---- stage X chunk for 2 batches (f32 -> f16 pairs) ----
        #pragma unroll
        for (int r = 0; r < 2; ++r) {
            const float4 xv = ((const float4*)(X + ((size_t)(b0 + r) * TT + t0) * DD))[tid];
            ((uint2*)Xs)[r * 512 + tid] = make_uint2(pkf16(xv.x, xv.y), pkf16(xv.z, xv.w));
        }
        bar_lgkm();

        // ---- xw[p][t][c] = X@Wslice + bias; thread (c,s): p=s>>1, th=s&1 ----
        {
            const int p = s >> 1, th = s & 1;
            float acc[8];
            #pragma unroll
            for (int t = 0; t < 8; ++t) acc[t] = bc;
            #pragma unroll
            for (int k8 = 0; k8 < 16; ++k8) {
                const uint4 w4 = Wlds4[c * 16 + (k8 ^ (c & 15))];
                #pragma unroll
                for (int t = 0; t < 8; ++t) {
                    const uint4 xg = *(const uint4*)((const char*)Xs +
                                     ((p * 16 + th * 8 + t) << 8) + (k8 << 4));
                    acc[t] = FDOT2(u2h(xg.x), u2h(w4.x), acc[t]);
                    acc[t] = FDOT2(u2h(xg.y), u2h(w4.y), acc[t]);
                    acc[t] = FDOT2(u2h(xg.z), u2h(w4.z), acc[t]);
                    acc[t] = FDOT2(u2h(xg.w), u2h(w4.w), acc[t]);
                }
            }
            #pragma unroll
            for (int t = 0; t < 8; ++t) xw[p][th * 8 + t][c] = acc[t];
        }
        bar_lgkm();

        // ---- TC recurrent steps, batch-pipelined slots ----
        for (int tt2 = 0; tt2 < TC; ++tt2) {
            const int tau = t0 + tt2;

            // ===== slot1: phase A for b0 (uses hsh[0..255] = h_b0[tau]) =====
            {
                float a = (s == 0) ? xw[0][tt2][c] : 0.0f;
                #pragma unroll
                for (int ii = 0; ii < 8; ++ii) {
                    const uint4 ug = Ulds4[c * 32 + ((s * 8 + ii) ^ (c & 31))];
                    const uint4 hg = *(const uint4*)((const char*)hsh + (s << 7) + (ii << 4));
                    a = FDOT2(u2h(ug.x), u2h(hg.x), a);
                    a = FDOT2(u2h(ug.y), u2h(hg.y), a);
                    a = FDOT2(u2h(ug.z), u2h(hg.z), a);
                    a = FDOT2(u2h(ug.w), u2h(hg.w), a);
                }
                gvp[s][c] = a;
            }
            bar_lgkm();

            // ===== slot2: gates b0 + publish P0(tau+1)  ||  poll P1(tau) ====
            if (wave == 0) {
                if (lane < 32) {
                    const int j = lane;
                    float gi = 0.f, gf = 0.f, gg = 0.f, go = 0.f;
                    #pragma unroll
                    for (int q = 0; q < 4; ++q) {
                        gi += gvp[q][j];       gf += gvp[q][32 + j];
                        gg += gvp[q][64 + j];  go += gvp[q][96 + j];
                    }
                    const float it = sigf(gi), ft = sigf(gf);
                    const float gt = tanh_fast(gg), ot = sigf(go);
                    c_reg0 = fmaf(ft, c_reg0, it * gt);
                    const float hn = ot * tanh_fast(c_reg0);
                    h_last0 = hn;
                    const unsigned long long pkt =
                        ((unsigned long long)(unsigned)(tau + 1) << 32) |
                        (unsigned long long)__float_as_uint(hn);
                    __hip_atomic_store(&hglob[(size_t)(slotbase + ((tau + 1) & 1)) * 64 + j],
                                       pkt, __ATOMIC_RELAXED, __HIP_MEMORY_SCOPE_AGENT);
                    out[obase0 + (size_t)tau * HH + j] = hn;
                    hsh[(g << 5) + j] = f16b(hn);
                }
            } else if (tau >= 1 && lane < 32) {
                const int pg = (g + wave) & 7;
                const unsigned long long* q =
                    &hglob[(size_t)((((pair << 3) + pg) << 1) + (tau & 1)) * 64 + 32 + lane];
                unsigned long long v; int spins = 0;
                do {
                    v = __hip_atomic_load(q, __ATOMIC_RELAXED, __HIP_MEMORY_SCOPE_AGENT);
                    if (++spins > (1 << 20)) break;      // anti-hang
                } while ((unsigned)(v >> 32) != (unsigned)tau);
                hsh[256 + (pg << 5) + lane] = f16b(__uint_as_float((unsigned)v));
            }
            bar_lgkm();

            // ===== slot3: phase A for b1 (uses hsh[256..511] = h_b1[tau]) ===
            {
                float a = (s == 0) ? xw[1][tt2][c] : 0.0f;
                #pragma unroll
                for (int ii = 0; ii < 8; ++ii) {
                    const uint4 ug = Ulds4[c * 32 + ((s * 8 + ii) ^ (c & 31))];
                    const uint4 hg = *(const uint4*)((const char*)hsh + 512 + (s << 7) + (ii << 4));
                    a = FDOT2(u2h(ug.x), u2h(hg.x), a);
                    a = FDOT2(u2h(ug.y), u2h(hg.y), a);
                    a = FDOT2(u2h(ug.z), u2h(hg.z), a);
                    a = FDOT2(u2h(ug.w), u2h(hg.w), a);
                }
                gvp[s][c] = a;
            }
            bar_lgkm();

            // ===== slot4: gates b1 + publish P1(tau+1)  ||  poll P0(tau+1) ==
            if (wave == 0) {
                if (lane < 32) {
                    const int j = lane;
                    float gi = 0.f, gf = 0.f, gg = 0.f, go = 0.f;
                    #pragma unroll
                    for (int q = 0; q < 4; ++q) {
                        gi += gvp[q][j];       gf += gvp[q][32 + j];
                        gg += gvp[q][64 + j];  go += gvp[q][96 + j];
                    }
                    const float it = sigf(gi), ft = sigf(gf);
                    const float gt = tanh_fast(gg), ot = sigf(go);
                    c_reg1 = fmaf(ft, c_reg1, it * gt);
                    const float hn = ot * tanh_fast(c_reg1);
                    h_last1 = hn;
                    const unsigned long long pkt =
                        ((unsigned long long)(unsigned)(tau + 1) << 32) |
                        (unsigned long long)__float_as_uint(hn);
                    __hip_atomic_store(&hglob[(size_t)(slotbase + ((tau + 1) & 1)) * 64 + 32 + j],
                                       pkt, __ATOMIC_RELAXED, __HIP_MEMORY_SCOPE_AGENT);
                    out[obase1 + (size_t)tau * HH + j] = hn;
                    hsh[256 + (g << 5) + j] = f16b(hn);
                }
            } else if (tau < TT - 1 && lane < 32) {
                const int pg = (g + wave) & 7;
                const unsigned long long* q =
                    &hglob[(size_t)((((pair << 3) + pg) << 1) + ((tau + 1) & 1)) * 64 + lane];
                unsigned long long v; int spins = 0;
                do {
                    v = __hip_atomic_load(q, __ATOMIC_RELAXED, __HIP_MEMORY_SCOPE_AGENT);
                    if (++spins > (1 << 20)) break;      // anti-hang
                } while ((unsigned)(v >> 32) != (unsigned)(tau + 1));
                hsh[(pg << 5) + lane] = f16b(__uint_as_float((unsigned)v));
            }
            bar_lgkm();
        }
    }

    if (wave == 0 && lane < 32) {
        const size_t base = (size_t)BB * TT * HH;
        out[base + (size_t)b0 * HH + (g << 5) + lane] = h_last0;
        out[base + (size_t)(b0 + 1) * HH + (g << 5) + lane] = h_last1;
        out[base + (size_t)BB * HH + (size_t)b0 * HH + (g << 5) + lane] = c_reg0;
        out[base + (size_t)BB * HH + (size_t)(b0 + 1) * HH + (g << 5) + lane] = c_reg1;
    }
}

// ================= R5 fallback (4 blocks/batch, flag+data) ==================
__global__ void zero_flags(int* flags) {
    flags[blockIdx.x * 256 + threadIdx.x] = 0;
}

__global__ void __launch_bounds__(256)
pack_cols(const float* __restrict__ src, unsigned short* __restrict__ dst, int K)
{
    const int g = blockIdx.x, kb = blockIdx.y, c = threadIdx.x;
    const int gc = ((c >> 6) << 8) + (g << 6) + (c & 63);
    unsigned int* d32 = (unsigned int*)dst;
    const int dbase = ((g << 8) + c) * K + kb * 64;
    for (int kk = 0; kk < 64; kk += 2) {
        const float a = src[(size_t)(kb * 64 + kk) * G4 + gc];
        const float b = src[(size_t)(kb * 64 + kk + 1) * G4 + gc];
        d32[(dbase + kk) >> 1] = pkf16(a, b);
    }
}

extern "C" __global__ void __launch_bounds__(512, 2)
lstm_sync(const float* __restrict__ X, const unsigned short* __restrict__ Upack,
          const unsigned short* __restrict__ Wpack, const float* __restrict__ bias,
          const float* __restrict__ h0, const float* __restrict__ c0,
          unsigned int* __restrict__ hglob, int* __restrict__ flags,
          float* __restrict__ out)
{
    __shared__ uint4 Ulds4[HH * 32];
    __shared__ float xw[TC][256];
    __shared__ __align__(16) unsigned short Xs[TC * DD];
    __shared__ float gvp[2][256];
    __shared__ __align__(16) unsigned short hsh[HH];

    const int b = blockIdx.x & 63;
    const int g = blockIdx.x >> 6;
    const int tid = threadIdx.x;
    const int wave = tid >> 6, lane = tid & 63;
    const int c = tid & 255, s = tid >> 8;
    const int gc = ((c >> 6) << 8) + (g << 6) + (c & 63);
    const int fbase = b * 4;

    {
        const uint4* Usrc = (const uint4*)(Upack + (size_t)g * 65536);
        #pragma unroll
        for (int i = 0; i < 16; ++i) {
            const int idx = i * 512 + tid;
            const int cc = idx >> 5, k8 = idx & 31;
            Ulds4[cc * 32 + (k8 ^ (cc & 31))] = Usrc[idx];
        }
    }
    if (tid < HH) hsh[tid] = f16b(h0[b * HH + tid]);
    float c_reg = 0.0f, h_last = 0.0f;
    if (wave == 0) {
        c_reg = c0[b * HH + (g << 6) + lane];
        h_last = h0[b * HH + (g << 6) + lane];
    }
    const float bc = bias[gc];
    __syncthreads();

    const unsigned short* Wg = Wpack + (size_t)g * 32768;

    for (int chunk = 0; chunk < TT / TC; ++chunk) {
        const int t0 = chunk * TC;
        {
            const float4 xv = ((const float4*)(X + ((size_t)b * TT + t0) * DD))[tid];
            ((uint2*)Xs)[tid] = make_uint2(pkf16(xv.x, xv.y), pkf16(xv.z, xv.w));
        }
        __syncthreads();
        {
            float acc[8];
            #pragma unroll
            for (int t = 0; t < 8; ++t) acc[t] = bc;
            const uint4* Wc = (const uint4*)(Wg + (size_t)c * 128);
            #pragma unroll
            for (int k8 = 0; k8 < 16; ++k8) {
                const uint4 w4 = Wc[k8];
                #pragma unroll
                for (int t = 0; t < 8; ++t) {
                    const uint4 xg = *(const uint4*)((const char*)Xs + (s * 8 + t) * 256 + (k8 << 4));
                    acc[t] = FDOT2(u2h(xg.x), u2h(w4.x), acc[t]);
                    acc[t] = FDOT2(u2h(xg.y), u2h(w4.y), acc[t]);
                    acc[t] = FDOT2(u2h(xg.z), u2h(w4.z), acc[t]);
                    acc[t] = FDOT2(u2h(xg.w), u2h(w4.w), acc[t]);
                }
            }
            #pragma unroll
            for (int t = 0; t < 8; ++t) xw[s * 8 + t][c] = acc[t];
        }
        __syncthreads();

        for (int tt = 0; tt < TC; ++tt) {
            const int tau = t0 + tt;
            {
                float a0 = (s == 0) ? xw[tt][c] : 0.0f;
                float a1 = 0.0f;
                const int kbase = s << 4;
                #pragma unroll
                for (int i = 0; i < 16; ++i) {
                    const int k8 = kbase + i;
                    const uint4 ug = Ulds4[c * 32 + (k8 ^ (c & 31))];
                    const uint4 hg = *(const uint4*)((const char*)hsh + (k8 << 4));
                    a0 = FDOT2(u2h(ug.x), u2h(hg.x), a0);
                    a1 = FDOT2(u2h(ug.y), u2h(hg.y), a1);
                    a0 = FDOT2(u2h(ug.z), u2h(hg.z), a0);
                    a1 = FDOT2(u2h(ug.w), u2h(hg.w), a1);
                }
                gvp[s][c] = a0 + a1;
            }
            __syncthreads();

            const int par = (tau + 1) & 1;
            if (wave == 0) {
                const int j = lane;
                const float gi = gvp[0][j]       + gvp[1][j];
                const float gf = gvp[0][64 + j]  + gvp[1][64 + j];
                const float gg = gvp[0][128 + j] + gvp[1][128 + j];
                const float go = gvp[0][192 + j] + gvp[1][192 + j];
                const float it = sigf(gi), ft = sigf(gf);
                const float gt = tanh_fast(gg), ot = sigf(go);
                c_reg = fmaf(ft, c_reg, it * gt);
                const float hn = ot * tanh_fast(c_reg);
                h_last = hn;
                const float lo = __shfl(hn, 2 * j);
                const float hi = __shfl(hn, 2 * j + 1);
                if (j < 32) {
                    __hip_atomic_store(&hglob[(((fbase + g) << 1) + par) * 32 + j],
                                       pkf16(lo, hi),
                                       __ATOMIC_RELAXED, __HIP_MEMORY_SCOPE_AGENT);
                }
                asm volatile("s_waitcnt vmcnt(0)" ::: "memory");
                if (j == 0) {
                    __hip_atomic_store(&flags[(fbase + g) * 8], tau + 1,
                                       __ATOMIC_RELAXED, __HIP_MEMORY_SCOPE_AGENT);
                }
                out[((size_t)b * TT + tau) * HH + (g << 6) + j] = hn;
                hsh[(g << 6) + j] = f16b(hn);
            } else if (wave <= 3 && tau < TT - 1) {
                const int pg = (g + wave) & 3;
                int spins = 0;
                while (__hip_atomic_load(&flags[(fbase + pg) * 8], __ATOMIC_RELAXED,
                                         __HIP_MEMORY_SCOPE_AGENT) < tau + 1) {
                    if (++spins > (1 << 20)) break;
                }
                if (lane < 32) {
                    const unsigned int pv = __hip_atomic_load(
                        &hglob[(((fbase + pg) << 1) + par) * 32 + lane],
                        __ATOMIC_RELAXED, __HIP_MEMORY_SCOPE_AGENT);
                    ((unsigned int*)hsh)[(pg << 5) + lane] = pv;
                }
            }
            __syncthreads();
        }
    }

    if (wave == 0) {
        const size_t base = (size_t)BB * TT * HH;
        out[base + (size_t)b * HH + (g << 6) + lane] = h_last;
        out[base + (size_t)BB * HH + (size_t)b * HH + (g << 6) + lane] = c_reg;
    }
}

// ===================== R2 fallback (f32, no workspace) ======================
extern "C" __global__ void __launch_bounds__(512)
lstm_persist(const float* __restrict__ X, const float* __restrict__ W,
             const float* __restrict__ U, const float* __restrict__ bias,
             const float* __restrict__ h0, const float* __restrict__ c0,
             float* __restrict__ out)
{
    __shared__ float xw[TC][G4];
    __shared__ float Xs[TC][DD];
    __shared__ float hsh[HH];
    __shared__ float gv[G4];

    const int b = blockIdx.x;
    const int tid = threadIdx.x;
    const float2* __restrict__ U2 = reinterpret_cast<const float2*>(U);
    const float2* __restrict__ W2 = reinterpret_cast<const float2*>(W);

    float c_reg = 0.0f;
    if (tid < HH) { hsh[tid] = h0[b * HH + tid]; c_reg = c0[b * HH + tid]; }
    const float2 bs = reinterpret_cast<const float2*>(bias)[tid];
    __syncthreads();

    for (int chunk = 0; chunk < TT / TC; ++chunk) {
        const int t0 = chunk * TC;
        {
            const float4* src = reinterpret_cast<const float4*>(X + ((size_t)b * TT + t0) * DD);
            float4* dst = reinterpret_cast<float4*>(&Xs[0][0]);
            for (int i = tid; i < TC * DD / 4; i += 512) dst[i] = src[i];
        }
        __syncthreads();
        float acc0[TC], acc1[TC];
        #pragma unroll
        for (int t = 0; t < TC; ++t) { acc0[t] = bs.x; acc1[t] = bs.y; }
        for (int kk = 0; kk < DD; kk += 4) {
            const float2 w0 = W2[(size_t)(kk + 0) * (G4 / 2) + tid];
            const float2 w1 = W2[(size_t)(kk + 1) * (G4 / 2) + tid];
            const float2 w2 = W2[(size_t)(kk + 2) * (G4 / 2) + tid];
            const float2 w3 = W2[(size_t)(kk + 3) * (G4 / 2) + tid];
            #pragma unroll
            for (int t = 0; t < TC; ++t) {
                const float4 xv = *reinterpret_cast<const float4*>(&Xs[t][kk]);
                acc0[t] = fmaf(xv.x, w0.x, acc0[t]); acc1[t] = fmaf(xv.x, w0.y, acc1[t]);
                acc0[t] = fmaf(xv.y, w1.x, acc0[t]); acc1[t] = fmaf(xv.y, w1.y, acc1[t]);
                acc0[t] = fmaf(xv.z, w2.x, acc0[t]); acc1[t] = fmaf(xv.z, w2.y, acc1[t]);
                acc0[t] = fmaf(xv.w, w3.x, acc0[t]); acc1[t] = fmaf(xv.w, w3.y, acc1[t]);
            }
        }
        #pragma unroll
        for (int t = 0; t < TC; ++t)
            *reinterpret_cast<float2*>(&xw[t][2 * tid]) = make_float2(acc0[t], acc1[t]);
        __syncthreads();

        for (int t = 0; t < TC; ++t) {
            const float2 x2 = *reinterpret_cast<const float2*>(&xw[t][2 * tid]);
            float a0 = x2.x, a1 = x2.y;
            #pragma unroll 4
            for (int k = 0; k < HH; k += 4) {
                const float4 hk = *reinterpret_cast<const float4*>(&hsh[k]);
                const float2 u0 = U2[(size_t)(k + 0) * (G4 / 2) + tid];
                const float2 u1 = U2[(size_t)(k + 1) * (G4 / 2) + tid];
                const float2 u2 = U2[(size_t)(k + 2) * (G4 / 2) + tid];
                const float2 u3 = U2[(size_t)(k + 3) * (G4 / 2) + tid];
                a0 = fmaf(hk.x, u0.x, a0); a1 = fmaf(hk.x, u0.y, a1);
                a0 = fmaf(hk.y, u1.x, a0); a1 = fmaf(hk.y, u1.y, a1);
                a0 = fmaf(hk.z, u2.x, a0); a1 = fmaf(hk.z, u2.y, a1);
                a0 = fmaf(hk.w, u3.x, a0); a1 = fmaf(hk.w, u3.y, a1);
            }
            *reinterpret_cast<float2*>(&gv[2 * tid]) = make_float2(a0, a1);
            __syncthreads();
            if (tid < HH) {
                const float it = sigf(gv[tid]);
                const float ft = sigf(gv[tid + HH]);
                const float gt = tanh_fast(gv[tid + 2 * HH]);
                const float ot = sigf(gv[tid + 3 * HH]);
                c_reg = fmaf(ft, c_reg, it * gt);
                const float hn = ot * tanh_fast(c_reg);
                hsh[tid] = hn;
                out[((size_t)b * TT + (t0 + t)) * HH + tid] = hn;
            }
            __syncthreads();
        }
    }
    if (tid < HH) {
        const size_t base = (size_t)BB * TT * HH;
        out[base + (size_t)b * HH + tid] = hsh[tid];
        out[base + (size_t)BB * HH + (size_t)b * HH + tid] = c_reg;
    }
}

extern "C" void kernel_launch(void* const* d_in, const int* in_sizes, int n_in,
                              void* d_out, int out_size, void* d_ws, size_t ws_size,
                              hipStream_t stream) {
    const float* X    = (const float*)d_in[0];
    const float* W    = (const float*)d_in[1];
    const float* U    = (const float*)d_in[2];
    const float* bias = (const float*)d_in[3];
    const float* h0   = (const float*)d_in[4];
    const float* c0   = (const float*)d_in[5];
    float* out = (float*)d_out;
    (void)in_sizes; (void)n_in; (void)out_size;

    // --- R7 path: 1 MB workspace ---
    const size_t upk7 = 512 * 1024;    // Upack f16 [8][128][256]
    const size_t wpk7 = 256 * 1024;    // Wpack f16 [8][128][128]
    const size_t hgl7 = 256 * 1024;    // hglob u64 [32][8][2][2][32]
    if (ws_size >= upk7 + wpk7 + hgl7) {
        unsigned short* Upack = (unsigned short*)d_ws;
        unsigned short* Wpack = (unsigned short*)((char*)d_ws + upk7);
        unsigned long long* hglob = (unsigned long long*)((char*)d_ws + upk7 + wpk7);
        zero_hglob<<<dim3(128), dim3(256), 0, stream>>>(hglob);
        pack_slices<<<dim3(8, 4), dim3(128), 0, stream>>>(U, Upack, 256);
        pack_slices<<<dim3(8, 2), dim3(128), 0, stream>>>(W, Wpack, 128);
        lstm_pipe<<<dim3(256), dim3(512), 0, stream>>>(
            X, Upack, Wpack, bias, h0, c0, hglob, out);
        return;
    }

    // --- R5 fallback: 840.5 KB ---
    const size_t upk = 512 * 1024;
    const size_t wpk = 256 * 1024;
    const size_t hgl = 64 * 1024;
    const size_t flg = 8 * 1024;
    if (ws_size >= upk + wpk + hgl + flg) {
        unsigned short* Upack = (unsigned short*)d_ws;
        unsigned short* Wpack = (unsigned short*)((char*)d_ws + upk);
        unsigned int*   hglob = (unsigned int*)((char*)d_ws + upk + wpk);
        int*            flags = (int*)((char*)d_ws + upk + wpk + hgl);
        zero_flags<<<dim3(8), dim3(256), 0, stream>>>(flags);
        pack_cols<<<dim3(4, 4), dim3(256), 0, stream>>>(U, Upack, 256);
        pack_cols<<<dim3(4, 2), dim3(256), 0, stream>>>(W, Wpack, 128);
        lstm_sync<<<dim3(256), dim3(512), 0, stream>>>(
            X, Upack, Wpack, bias, h0, c0, hglob, flags, out);
        return;
    }

    // --- R2 fallback: no workspace ---
    lstm_persist<<<dim3(BB), dim3(512), 0, stream>>>(X, W, U, bias, h0, c0, out);
}